// Round 8
// baseline (420.717 us; speedup 1.0000x reference)
//
#include <hip/hip_runtime.h>
#include <hip/hip_bf16.h>
#include <math.h>

#define NHEADS 10

typedef unsigned short ushort_t;
typedef unsigned int uint_t;

__device__ __forceinline__ float bu2f(ushort_t u){ return __uint_as_float(((uint_t)u)<<16); }
__device__ __forceinline__ ushort_t f2bu(float f){
    uint_t b = __float_as_uint(f);
    return (ushort_t)((b + 0x7FFFu + ((b>>16)&1u)) >> 16);   // RNE
}

// ---------------- CSR build ----------------
__global__ void k_count(const int* eidx, int E, int N, int* cnt){
    int e = blockIdx.x*blockDim.x + threadIdx.x;
    int ET = E + N;
    if(e >= ET) return;
    int d = (e < E) ? eidx[E + e] : (e - E);
    atomicAdd(&cnt[d], 1);
}

__global__ void k_scan(int* cnt, int N, int ET, int* indptr){
    __shared__ int lds[1024];
    int t = threadIdx.x;
    int chunk = (N + 1023)/1024;
    int base = t*chunk;
    int s = 0;
    for(int i=0;i<chunk;i++){ int idx=base+i; if(idx<N) s += cnt[idx]; }
    lds[t]=s;
    __syncthreads();
    for(int off=1; off<1024; off<<=1){
        int v = (t>=off)? lds[t-off] : 0;
        __syncthreads();
        lds[t]+=v;
        __syncthreads();
    }
    int run = lds[t]-s;
    for(int i=0;i<chunk;i++){
        int idx=base+i;
        if(idx<N){
            int c = cnt[idx];
            indptr[idx]=run;
            cnt[idx]=run;
            run += c;
        }
    }
    if(t==0) indptr[N]=ET;
}

__global__ void k_fill(const int* eidx, int E, int N, int* cursor, int* srcs){
    int e = blockIdx.x*blockDim.x + threadIdx.x;
    int ET = E + N;
    if(e >= ET) return;
    int s, d;
    if(e < E){ s = eidx[e]; d = eidx[E+e]; } else { s = e-E; d = e-E; }
    int pos = atomicAdd(&cursor[d], 1);
    srcs[pos] = s;
}

// wave-parallel bitonic sort of each node's src segment (1 wave / node)
__global__ void k_sortw(const int* indptr, int* srcs, int N){
    int wid  = (blockIdx.x*blockDim.x + threadIdx.x) >> 6;
    int lane = threadIdx.x & 63;
    if(wid >= N) return;
    int p0 = indptr[wid], p1 = indptr[wid+1];
    int deg = p1 - p0;
    if(deg <= 1) return;
    if(deg <= 64){
        int v = (lane < deg) ? srcs[p0+lane] : 0x7FFFFFFF;
        #pragma unroll
        for(int k=2; k<=64; k<<=1){
            #pragma unroll
            for(int j=k>>1; j>0; j>>=1){
                int partner = __shfl_xor(v, j, 64);
                bool dir   = ((lane & k) == 0);
                bool small = ((lane & j) == 0);
                int mn = min(v, partner), mx = max(v, partner);
                v = (dir == small) ? mn : mx;
            }
        }
        if(lane < deg) srcs[p0+lane] = v;
    } else if(lane == 0){               // safety fallback, statistically never
        for(int i=p0+1;i<p1;i++){
            int v2 = srcs[i]; int j=i-1;
            while(j>=p0 && srcs[j]>v2){ srcs[j+1]=srcs[j]; j--; }
            srcs[j+1]=v2;
        }
    }
}

// ---------------- fc0: [N,24]@[24,16]+b, ELU ----------------
__global__ void k_fc0(const float* x, const float* W0, const float* b0, float* out, int N){
    int idx = blockIdx.x*blockDim.x+threadIdx.x;
    if(idx >= N*16) return;
    int n = idx>>4, c = idx&15;
    float acc = b0[c];
    #pragma unroll
    for(int k=0;k<24;k++) acc += x[n*24+k] * W0[k*16+c];
    out[idx] = acc>0.f ? acc : expm1f(acc);
}

// ---------------- tiled GEMM: C[N,HC] = A[N,K] @ B[K,HC] ----------------
// 64x64 tile / block, 256 threads, 4x4 micro-tile. unroll 8 (full unroll spilled: R3).
template<int K, int EPI, int OUTBF16>
__global__ void __launch_bounds__(256, 2)
k_gemm(const float* __restrict__ A, const float* __restrict__ B,
       const float* __restrict__ bias, void* __restrict__ Cmat,
       int N, int HC){
    constexpr int KC = (K > 64) ? 64 : K;
    __shared__ float As[64][K+1];
    __shared__ float Bs[KC][68];

    int t = threadIdx.x;
    int row0 = blockIdx.x*64;
    int col0 = blockIdx.y*64;

    for(int i=t; i<64*K; i+=256){
        int r = i/K, k = i%K;
        int row = row0 + r;
        As[r][k] = (row < N) ? A[(size_t)row*K + k] : 0.f;
    }

    int tr = t>>4, tc = t&15;
    int r0 = tr*4, c0 = tc*4;

    float acc[4][4];
    #pragma unroll
    for(int i=0;i<4;i++)
        #pragma unroll
        for(int j=0;j<4;j++) acc[i][j]=0.f;

    for(int kb=0; kb<K; kb+=KC){
        __syncthreads();
        for(int i=t; i<KC*64; i+=256){
            int k = i>>6, c = i&63;
            Bs[k][c] = B[(size_t)(kb+k)*HC + col0 + c];
        }
        __syncthreads();
        #pragma unroll 8
        for(int k=0;k<KC;k++){
            float4 b = *(const float4*)&Bs[k][c0];
            float a0 = As[r0+0][kb+k];
            float a1 = As[r0+1][kb+k];
            float a2 = As[r0+2][kb+k];
            float a3 = As[r0+3][kb+k];
            acc[0][0] += a0*b.x; acc[0][1] += a0*b.y; acc[0][2] += a0*b.z; acc[0][3] += a0*b.w;
            acc[1][0] += a1*b.x; acc[1][1] += a1*b.y; acc[1][2] += a1*b.z; acc[1][3] += a1*b.w;
            acc[2][0] += a2*b.x; acc[2][1] += a2*b.y; acc[2][2] += a2*b.z; acc[2][3] += a2*b.w;
            acc[3][0] += a3*b.x; acc[3][1] += a3*b.y; acc[3][2] += a3*b.z; acc[3][3] += a3*b.w;
        }
    }

    #pragma unroll
    for(int i=0;i<4;i++){
        int row = row0 + r0 + i;
        if(row >= N) continue;
        float4 v;
        v.x = acc[i][0]; v.y = acc[i][1]; v.z = acc[i][2]; v.w = acc[i][3];
        if(EPI){
            v.x += bias[col0+c0+0]; v.y += bias[col0+c0+1];
            v.z += bias[col0+c0+2]; v.w += bias[col0+c0+3];
            v.x = v.x>0.f? v.x : expm1f(v.x);
            v.y = v.y>0.f? v.y : expm1f(v.y);
            v.z = v.z>0.f? v.z : expm1f(v.z);
            v.w = v.w>0.f? v.w : expm1f(v.w);
        }
        if(OUTBF16){
            ushort4 u;
            u.x = f2bu(v.x); u.y = f2bu(v.y); u.z = f2bu(v.z); u.w = f2bu(v.w);
            *(ushort4*)&((ushort_t*)Cmat)[(size_t)row*HC + col0 + c0] = u;
        } else {
            *(float4*)&((float*)Cmat)[(size_t)row*HC + col0 + c0] = v;
        }
    }
}

// ---------------- attention logits per (n,h), bf16 hf ----------------
template<int C>
__global__ void k_attn(const ushort_t* hf, const float* a_s, const float* a_d,
                       float* es, float* ed, int N){
    int idx = blockIdx.x*blockDim.x+threadIdx.x;
    if(idx >= N*NHEADS) return;
    int n = idx/NHEADS, h = idx%NHEADS;
    const uint4* hp = reinterpret_cast<const uint4*>(hf + (size_t)n*NHEADS*C + h*C);
    float s=0.f, d=0.f;
    #pragma unroll
    for(int cb=0; cb<C/8; cb++){
        uint4 q = hp[cb];
        uint_t uu[4] = {q.x, q.y, q.z, q.w};
        #pragma unroll
        for(int j=0;j<4;j++){
            float f0 = __uint_as_float(uu[j]<<16);
            float f1 = __uint_as_float(uu[j] & 0xFFFF0000u);
            int c = cb*8 + j*2;
            s += f0*a_s[h*C+c]   + f1*a_s[h*C+c+1];
            d += f0*a_d[h*C+c]   + f1*a_d[h*C+c+1];
        }
    }
    es[idx]=s; ed[idx]=d;
}

// ---------------- softmax stats: pass1 online max+den (caches leaky logit), pass2 normalize ----------------
__global__ void k_stats(const int* indptr, const int* srcs, const float* es, const float* ed,
                        float* wbuf, int N){
    int idx = blockIdx.x*blockDim.x+threadIdx.x;
    if(idx >= N*NHEADS) return;
    int n = idx/NHEADS, h = idx%NHEADS;
    int p0 = indptr[n], p1 = indptr[n+1];
    float edv = ed[idx];
    float m = -1e30f, den = 0.f;
    for(int p=p0;p<p1;p++){
        float v = es[srcs[p]*NHEADS+h] + edv;
        v = (v>=0.f)? v : 0.2f*v;
        wbuf[(size_t)p*NHEADS+h] = v;
        float nm = fmaxf(m, v);
        den = den*expf(m-nm) + expf(v-nm);
        m = nm;
    }
    float dinv = 1.f/(den+1e-16f);
    for(int p=p0;p<p1;p++){
        float v = wbuf[(size_t)p*NHEADS+h];
        wbuf[(size_t)p*NHEADS+h] = expf(v-m)*dinv;
    }
}

// ---------------- aggregation: bf16 hf gather, 8 channels/thread (uint4 loads) ----------------
template<int C>
__global__ void k_agg(const int* indptr, const int* srcs, const float* wbuf,
                      const ushort_t* hf, const float* bc, float* out, int N){
    constexpr int TPN = C/8;          // threads per node (8 bf16 channels each)
    constexpr int NPB = 256/TPN;      // nodes per block
    int local = threadIdx.x % TPN;
    int n = blockIdx.x*NPB + threadIdx.x/TPN;
    if(n>=N) return;
    int c8 = local*8;
    int p0=indptr[n], p1=indptr[n+1];
    float acc[8];
    #pragma unroll
    for(int i=0;i<8;i++) acc[i]=0.f;
    for(int p=p0;p<p1;p++){
        int s = srcs[p];
        const ushort_t* hp = hf + (size_t)s*NHEADS*C + c8;
        const float* wp = wbuf + (size_t)p*NHEADS;
        #pragma unroll
        for(int h=0;h<NHEADS;h++){
            uint4 q = *(const uint4*)(hp + h*C);
            float w = wp[h];
            acc[0] += w * __uint_as_float(q.x<<16);
            acc[1] += w * __uint_as_float(q.x & 0xFFFF0000u);
            acc[2] += w * __uint_as_float(q.y<<16);
            acc[3] += w * __uint_as_float(q.y & 0xFFFF0000u);
            acc[4] += w * __uint_as_float(q.z<<16);
            acc[5] += w * __uint_as_float(q.z & 0xFFFF0000u);
            acc[6] += w * __uint_as_float(q.w<<16);
            acc[7] += w * __uint_as_float(q.w & 0xFFFF0000u);
        }
    }
    float4 v0, v1;
    float* vv = &v0.x;
    #pragma unroll
    for(int i=0;i<8;i++){
        float v = acc[i]*(1.f/NHEADS) + bc[c8+i];
        v = v>0.f? v : expm1f(v);
        ((float*)&v0)[0]; // no-op to keep layout obvious
        if(i<4) ((float*)&v0)[i] = v; else ((float*)&v1)[i-4] = v;
    }
    (void)vv;
    *(float4*)&out[(size_t)n*C + c8]     = v0;
    *(float4*)&out[(size_t)n*C + c8 + 4] = v1;
}

// ---------------- head: logits 256->24 + log_softmax ----------------
__global__ void k_head(const float* hin, const float* W2, const float* b2v, float* out, int N){
    int grp  = threadIdx.x/32;
    int lane = threadIdx.x%32;
    int n = blockIdx.x*8 + grp;
    if(n>=N) return;
    float acc = -1e30f;
    if(lane < 24){
        acc = b2v[lane];
        for(int k=0;k<256;k++) acc += hin[n*256+k]*W2[k*24+lane];
    }
    float mx = acc;
    for(int off=16; off; off>>=1) mx = fmaxf(mx, __shfl_xor(mx, off, 32));
    float ex = (lane<24)? expf(acc-mx) : 0.f;
    float sm = ex;
    for(int off=16; off; off>>=1) sm += __shfl_xor(sm, off, 32);
    if(lane<24) out[n*24+lane] = acc - mx - logf(sm);
}

extern "C" void kernel_launch(void* const* d_in, const int* in_sizes, int n_in,
                              void* d_out, int out_size, void* d_ws, size_t ws_size,
                              hipStream_t stream) {
    const float* x   = (const float*)d_in[0];
    const int*  eidx = (const int*)d_in[1];
    const float* W0 = (const float*)d_in[3];  const float* b0 = (const float*)d_in[4];
    const float* Wc1= (const float*)d_in[5];  const float* as1= (const float*)d_in[6];
    const float* ad1= (const float*)d_in[7];  const float* bc1= (const float*)d_in[8];
    const float* Wc2= (const float*)d_in[9];  const float* as2= (const float*)d_in[10];
    const float* ad2= (const float*)d_in[11]; const float* bc2= (const float*)d_in[12];
    const float* Wc3= (const float*)d_in[13]; const float* as3= (const float*)d_in[14];
    const float* ad3= (const float*)d_in[15]; const float* bc3= (const float*)d_in[16];
    const float* W1 = (const float*)d_in[17]; const float* b1 = (const float*)d_in[18];
    const float* W2 = (const float*)d_in[19]; const float* b2 = (const float*)d_in[20];
    float* out = (float*)d_out;

    const int N  = in_sizes[0]/24;
    const int E  = in_sizes[1]/2;
    const int ET = E + N;

    char* w = (char*)d_ws;
    size_t off = 0;
    auto alloc = [&](size_t bytes)->void* {
        void* p = w + off;
        off = (off + bytes + 255) & ~(size_t)255;
        return p;
    };
    int*   cnt    = (int*)  alloc((size_t)N*4);
    int*   indptr = (int*)  alloc((size_t)(N+1)*4);
    int*   srcs   = (int*)  alloc((size_t)ET*4);
    float* es     = (float*)alloc((size_t)N*NHEADS*4);
    float* ed     = (float*)alloc((size_t)N*NHEADS*4);
    float* wbuf   = (float*)alloc((size_t)ET*NHEADS*4);
    float* nfA    = (float*)alloc((size_t)N*256*4);
    float* nfB    = (float*)alloc((size_t)N*256*4);
    ushort_t* hf  = (ushort_t*)alloc((size_t)N*1280*2);

    // CSR by dst
    hipMemsetAsync(cnt, 0, (size_t)N*4, stream);
    int gE = (ET+255)/256;
    k_count<<<gE,256,0,stream>>>(eidx, E, N, cnt);
    k_scan <<<1,1024,0,stream>>>(cnt, N, ET, indptr);
    k_fill <<<gE,256,0,stream>>>(eidx, E, N, cnt, srcs);
    k_sortw<<<((size_t)N*64+255)/256,256,0,stream>>>(indptr, srcs, N);

    int gNH = (N*NHEADS+255)/256;
    int gRow = (N+63)/64;

    // fc0
    k_fc0<<<(N*16+255)/256,256,0,stream>>>(x, W0, b0, nfA, N);

    // GAT1: 16 -> H x 32
    k_gemm<16,0,1><<<dim3(gRow,320/64),256,0,stream>>>(nfA, Wc1, nullptr, hf, N, 320);
    k_attn<32><<<gNH,256,0,stream>>>(hf, as1, ad1, es, ed, N);
    k_stats<<<gNH,256,0,stream>>>(indptr, srcs, es, ed, wbuf, N);
    k_agg<32><<<(N*4+255)/256,256,0,stream>>>(indptr, srcs, wbuf, hf, bc1, nfB, N);

    // GAT2: 32 -> H x 64
    k_gemm<32,0,1><<<dim3(gRow,640/64),256,0,stream>>>(nfB, Wc2, nullptr, hf, N, 640);
    k_attn<64><<<gNH,256,0,stream>>>(hf, as2, ad2, es, ed, N);
    k_stats<<<gNH,256,0,stream>>>(indptr, srcs, es, ed, wbuf, N);
    k_agg<64><<<(N*8+255)/256,256,0,stream>>>(indptr, srcs, wbuf, hf, bc2, nfA, N);

    // GAT3: 64 -> H x 128
    k_gemm<64,0,1><<<dim3(gRow,1280/64),256,0,stream>>>(nfA, Wc3, nullptr, hf, N, 1280);
    k_attn<128><<<gNH,256,0,stream>>>(hf, as3, ad3, es, ed, N);
    k_stats<<<gNH,256,0,stream>>>(indptr, srcs, es, ed, wbuf, N);
    k_agg<128><<<(N*16+255)/256,256,0,stream>>>(indptr, srcs, wbuf, hf, bc3, nfB, N);

    // fc1: [N,128]@[128,256] + bias + ELU (f32 out)
    k_gemm<128,1,0><<<dim3(gRow,256/64),256,0,stream>>>(nfB, W1, b1, nfA, N, 256);
    // head
    k_head<<<(N+7)/8,256,0,stream>>>(nfA, W2, b2, out, N);
}

// Round 9
// 390.289 us; speedup vs baseline: 1.0780x; 1.0780x over previous
//
#include <hip/hip_runtime.h>
#include <hip/hip_bf16.h>
#include <math.h>

#define NHEADS 10

typedef unsigned short ushort_t;
typedef unsigned int uint_t;

__device__ __forceinline__ float bu2f(ushort_t u){ return __uint_as_float(((uint_t)u)<<16); }
__device__ __forceinline__ ushort_t f2bu(float f){
    uint_t b = __float_as_uint(f);
    return (ushort_t)((b + 0x7FFFu + ((b>>16)&1u)) >> 16);   // RNE
}

// ---------------- CSR build ----------------
__global__ void k_count(const int* eidx, int E, int N, int* cnt){
    int e = blockIdx.x*blockDim.x + threadIdx.x;
    int ET = E + N;
    if(e >= ET) return;
    int d = (e < E) ? eidx[E + e] : (e - E);
    atomicAdd(&cnt[d], 1);
}

__global__ void k_scan(int* cnt, int N, int ET, int* indptr){
    __shared__ int lds[1024];
    int t = threadIdx.x;
    int chunk = (N + 1023)/1024;
    int base = t*chunk;
    int s = 0;
    for(int i=0;i<chunk;i++){ int idx=base+i; if(idx<N) s += cnt[idx]; }
    lds[t]=s;
    __syncthreads();
    for(int off=1; off<1024; off<<=1){
        int v = (t>=off)? lds[t-off] : 0;
        __syncthreads();
        lds[t]+=v;
        __syncthreads();
    }
    int run = lds[t]-s;
    for(int i=0;i<chunk;i++){
        int idx=base+i;
        if(idx<N){
            int c = cnt[idx];
            indptr[idx]=run;
            cnt[idx]=run;
            run += c;
        }
    }
    if(t==0) indptr[N]=ET;
}

__global__ void k_fill(const int* eidx, int E, int N, int* cursor, int* srcs){
    int e = blockIdx.x*blockDim.x + threadIdx.x;
    int ET = E + N;
    if(e >= ET) return;
    int s, d;
    if(e < E){ s = eidx[e]; d = eidx[E+e]; } else { s = e-E; d = e-E; }
    int pos = atomicAdd(&cursor[d], 1);
    srcs[pos] = s;
}

// wave-parallel bitonic sort of each node's src segment (1 wave / node)
__global__ void k_sortw(const int* indptr, int* srcs, int N){
    int wid  = (blockIdx.x*blockDim.x + threadIdx.x) >> 6;
    int lane = threadIdx.x & 63;
    if(wid >= N) return;
    int p0 = indptr[wid], p1 = indptr[wid+1];
    int deg = p1 - p0;
    if(deg <= 1) return;
    if(deg <= 64){
        int v = (lane < deg) ? srcs[p0+lane] : 0x7FFFFFFF;
        #pragma unroll
        for(int k=2; k<=64; k<<=1){
            #pragma unroll
            for(int j=k>>1; j>0; j>>=1){
                int partner = __shfl_xor(v, j, 64);
                bool dir   = ((lane & k) == 0);
                bool small = ((lane & j) == 0);
                int mn = min(v, partner), mx = max(v, partner);
                v = (dir == small) ? mn : mx;
            }
        }
        if(lane < deg) srcs[p0+lane] = v;
    } else if(lane == 0){               // safety fallback, statistically never
        for(int i=p0+1;i<p1;i++){
            int v2 = srcs[i]; int j=i-1;
            while(j>=p0 && srcs[j]>v2){ srcs[j+1]=srcs[j]; j--; }
            srcs[j+1]=v2;
        }
    }
}

// ---------------- fc0: [N,24]@[24,16]+b, ELU ----------------
__global__ void k_fc0(const float* x, const float* W0, const float* b0, float* out, int N){
    int idx = blockIdx.x*blockDim.x+threadIdx.x;
    if(idx >= N*16) return;
    int n = idx>>4, c = idx&15;
    float acc = b0[c];
    #pragma unroll
    for(int k=0;k<24;k++) acc += x[n*24+k] * W0[k*16+c];
    out[idx] = acc>0.f ? acc : expm1f(acc);
}

// ---------------- tiled GEMM: C[N,HC] = A[N,K] @ B[K,HC] ----------------
// 64x64 tile / block, 256 threads, 4x4 micro-tile. unroll 8 (full unroll spilled: R3).
template<int K, int EPI, int OUTBF16>
__global__ void __launch_bounds__(256, 2)
k_gemm(const float* __restrict__ A, const float* __restrict__ B,
       const float* __restrict__ bias, void* __restrict__ Cmat,
       int N, int HC){
    constexpr int KC = (K > 64) ? 64 : K;
    __shared__ float As[64][K+1];
    __shared__ float Bs[KC][68];

    int t = threadIdx.x;
    int row0 = blockIdx.x*64;
    int col0 = blockIdx.y*64;

    for(int i=t; i<64*K; i+=256){
        int r = i/K, k = i%K;
        int row = row0 + r;
        As[r][k] = (row < N) ? A[(size_t)row*K + k] : 0.f;
    }

    int tr = t>>4, tc = t&15;
    int r0 = tr*4, c0 = tc*4;

    float acc[4][4];
    #pragma unroll
    for(int i=0;i<4;i++)
        #pragma unroll
        for(int j=0;j<4;j++) acc[i][j]=0.f;

    for(int kb=0; kb<K; kb+=KC){
        __syncthreads();
        for(int i=t; i<KC*64; i+=256){
            int k = i>>6, c = i&63;
            Bs[k][c] = B[(size_t)(kb+k)*HC + col0 + c];
        }
        __syncthreads();
        #pragma unroll 8
        for(int k=0;k<KC;k++){
            float4 b = *(const float4*)&Bs[k][c0];
            float a0 = As[r0+0][kb+k];
            float a1 = As[r0+1][kb+k];
            float a2 = As[r0+2][kb+k];
            float a3 = As[r0+3][kb+k];
            acc[0][0] += a0*b.x; acc[0][1] += a0*b.y; acc[0][2] += a0*b.z; acc[0][3] += a0*b.w;
            acc[1][0] += a1*b.x; acc[1][1] += a1*b.y; acc[1][2] += a1*b.z; acc[1][3] += a1*b.w;
            acc[2][0] += a2*b.x; acc[2][1] += a2*b.y; acc[2][2] += a2*b.z; acc[2][3] += a2*b.w;
            acc[3][0] += a3*b.x; acc[3][1] += a3*b.y; acc[3][2] += a3*b.z; acc[3][3] += a3*b.w;
        }
    }

    #pragma unroll
    for(int i=0;i<4;i++){
        int row = row0 + r0 + i;
        if(row >= N) continue;
        float4 v;
        v.x = acc[i][0]; v.y = acc[i][1]; v.z = acc[i][2]; v.w = acc[i][3];
        if(EPI){
            v.x += bias[col0+c0+0]; v.y += bias[col0+c0+1];
            v.z += bias[col0+c0+2]; v.w += bias[col0+c0+3];
            v.x = v.x>0.f? v.x : expm1f(v.x);
            v.y = v.y>0.f? v.y : expm1f(v.y);
            v.z = v.z>0.f? v.z : expm1f(v.z);
            v.w = v.w>0.f? v.w : expm1f(v.w);
        }
        if(OUTBF16){
            ushort4 u;
            u.x = f2bu(v.x); u.y = f2bu(v.y); u.z = f2bu(v.z); u.w = f2bu(v.w);
            *(ushort4*)&((ushort_t*)Cmat)[(size_t)row*HC + col0 + c0] = u;
        } else {
            *(float4*)&((float*)Cmat)[(size_t)row*HC + col0 + c0] = v;
        }
    }
}

// ---------------- attention logits per (n,h), bf16 hf ----------------
template<int C>
__global__ void k_attn(const ushort_t* hf, const float* a_s, const float* a_d,
                       float* es, float* ed, int N){
    int idx = blockIdx.x*blockDim.x+threadIdx.x;
    if(idx >= N*NHEADS) return;
    int n = idx/NHEADS, h = idx%NHEADS;
    const uint4* hp = reinterpret_cast<const uint4*>(hf + (size_t)n*NHEADS*C + h*C);
    float s=0.f, d=0.f;
    #pragma unroll
    for(int cb=0; cb<C/8; cb++){
        uint4 q = hp[cb];
        uint_t uu[4] = {q.x, q.y, q.z, q.w};
        #pragma unroll
        for(int j=0;j<4;j++){
            float f0 = __uint_as_float(uu[j]<<16);
            float f1 = __uint_as_float(uu[j] & 0xFFFF0000u);
            int c = cb*8 + j*2;
            s += f0*a_s[h*C+c]   + f1*a_s[h*C+c+1];
            d += f0*a_d[h*C+c]   + f1*a_d[h*C+c+1];
        }
    }
    es[idx]=s; ed[idx]=d;
}

// ---------------- softmax stats: pass1 online max+den (caches leaky logit), pass2 normalize ----------------
__global__ void k_stats(const int* indptr, const int* srcs, const float* es, const float* ed,
                        float* wbuf, int N){
    int idx = blockIdx.x*blockDim.x+threadIdx.x;
    if(idx >= N*NHEADS) return;
    int n = idx/NHEADS, h = idx%NHEADS;
    int p0 = indptr[n], p1 = indptr[n+1];
    float edv = ed[idx];
    float m = -1e30f, den = 0.f;
    for(int p=p0;p<p1;p++){
        float v = es[srcs[p]*NHEADS+h] + edv;
        v = (v>=0.f)? v : 0.2f*v;
        wbuf[(size_t)p*NHEADS+h] = v;
        float nm = fmaxf(m, v);
        den = den*expf(m-nm) + expf(v-nm);
        m = nm;
    }
    float dinv = 1.f/(den+1e-16f);
    for(int p=p0;p<p1;p++){
        float v = wbuf[(size_t)p*NHEADS+h];
        wbuf[(size_t)p*NHEADS+h] = expf(v-m)*dinv;
    }
}

// ---------------- aggregation: one wave per node ----------------
// lane = (edge-group eg, channel-group local): TPN=C/8 channel threads (uint4 = 8 bf16),
// EG = 64/TPN edge groups striding the edge list. shfl_xor tree folds edge groups.
template<int C>
__global__ void k_agg(const int* indptr, const int* srcs, const float* wbuf,
                      const ushort_t* hf, const float* bc, float* out, int N){
    constexpr int TPN = C/8;
    constexpr int EG  = 64/TPN;
    int n    = (blockIdx.x*blockDim.x + threadIdx.x) >> 6;   // wave per node
    int lane = threadIdx.x & 63;
    if(n >= N) return;
    int local = lane % TPN;
    int eg    = lane / TPN;
    int c8 = local*8;
    int p0=indptr[n], p1=indptr[n+1];
    float acc[8];
    #pragma unroll
    for(int i=0;i<8;i++) acc[i]=0.f;
    for(int p=p0+eg; p<p1; p+=EG){
        int s = srcs[p];
        const ushort_t* hp = hf + (size_t)s*NHEADS*C + c8;
        const float* wp = wbuf + (size_t)p*NHEADS;
        #pragma unroll
        for(int h=0;h<NHEADS;h++){
            uint4 q = *(const uint4*)(hp + h*C);
            float w = wp[h];
            acc[0] += w * __uint_as_float(q.x<<16);
            acc[1] += w * __uint_as_float(q.x & 0xFFFF0000u);
            acc[2] += w * __uint_as_float(q.y<<16);
            acc[3] += w * __uint_as_float(q.y & 0xFFFF0000u);
            acc[4] += w * __uint_as_float(q.z<<16);
            acc[5] += w * __uint_as_float(q.z & 0xFFFF0000u);
            acc[6] += w * __uint_as_float(q.w<<16);
            acc[7] += w * __uint_as_float(q.w & 0xFFFF0000u);
        }
    }
    // fold edge groups (whole wave active: n uniform per wave)
    #pragma unroll
    for(int s=TPN; s<64; s<<=1){
        #pragma unroll
        for(int i=0;i<8;i++) acc[i] += __shfl_xor(acc[i], s, 64);
    }
    if(eg == 0){
        float4 v0, v1;
        #pragma unroll
        for(int i=0;i<8;i++){
            float v = acc[i]*(1.f/NHEADS) + bc[c8+i];
            v = v>0.f? v : expm1f(v);
            if(i<4) ((float*)&v0)[i] = v; else ((float*)&v1)[i-4] = v;
        }
        *(float4*)&out[(size_t)n*C + c8]     = v0;
        *(float4*)&out[(size_t)n*C + c8 + 4] = v1;
    }
}

// ---------------- head: logits 256->24 + log_softmax ----------------
__global__ void k_head(const float* hin, const float* W2, const float* b2v, float* out, int N){
    int grp  = threadIdx.x/32;
    int lane = threadIdx.x%32;
    int n = blockIdx.x*8 + grp;
    if(n>=N) return;
    float acc = -1e30f;
    if(lane < 24){
        acc = b2v[lane];
        for(int k=0;k<256;k++) acc += hin[n*256+k]*W2[k*24+lane];
    }
    float mx = acc;
    for(int off=16; off; off>>=1) mx = fmaxf(mx, __shfl_xor(mx, off, 32));
    float ex = (lane<24)? expf(acc-mx) : 0.f;
    float sm = ex;
    for(int off=16; off; off>>=1) sm += __shfl_xor(sm, off, 32);
    if(lane<24) out[n*24+lane] = acc - mx - logf(sm);
}

extern "C" void kernel_launch(void* const* d_in, const int* in_sizes, int n_in,
                              void* d_out, int out_size, void* d_ws, size_t ws_size,
                              hipStream_t stream) {
    const float* x   = (const float*)d_in[0];
    const int*  eidx = (const int*)d_in[1];
    const float* W0 = (const float*)d_in[3];  const float* b0 = (const float*)d_in[4];
    const float* Wc1= (const float*)d_in[5];  const float* as1= (const float*)d_in[6];
    const float* ad1= (const float*)d_in[7];  const float* bc1= (const float*)d_in[8];
    const float* Wc2= (const float*)d_in[9];  const float* as2= (const float*)d_in[10];
    const float* ad2= (const float*)d_in[11]; const float* bc2= (const float*)d_in[12];
    const float* Wc3= (const float*)d_in[13]; const float* as3= (const float*)d_in[14];
    const float* ad3= (const float*)d_in[15]; const float* bc3= (const float*)d_in[16];
    const float* W1 = (const float*)d_in[17]; const float* b1 = (const float*)d_in[18];
    const float* W2 = (const float*)d_in[19]; const float* b2 = (const float*)d_in[20];
    float* out = (float*)d_out;

    const int N  = in_sizes[0]/24;
    const int E  = in_sizes[1]/2;
    const int ET = E + N;

    char* w = (char*)d_ws;
    size_t off = 0;
    auto alloc = [&](size_t bytes)->void* {
        void* p = w + off;
        off = (off + bytes + 255) & ~(size_t)255;
        return p;
    };
    int*   cnt    = (int*)  alloc((size_t)N*4);
    int*   indptr = (int*)  alloc((size_t)(N+1)*4);
    int*   srcs   = (int*)  alloc((size_t)ET*4);
    float* es     = (float*)alloc((size_t)N*NHEADS*4);
    float* ed     = (float*)alloc((size_t)N*NHEADS*4);
    float* wbuf   = (float*)alloc((size_t)ET*NHEADS*4);
    float* nfA    = (float*)alloc((size_t)N*256*4);
    float* nfB    = (float*)alloc((size_t)N*256*4);
    ushort_t* hf  = (ushort_t*)alloc((size_t)N*1280*2);

    // CSR by dst
    hipMemsetAsync(cnt, 0, (size_t)N*4, stream);
    int gE = (ET+255)/256;
    k_count<<<gE,256,0,stream>>>(eidx, E, N, cnt);
    k_scan <<<1,1024,0,stream>>>(cnt, N, ET, indptr);
    k_fill <<<gE,256,0,stream>>>(eidx, E, N, cnt, srcs);
    k_sortw<<<((size_t)N*64+255)/256,256,0,stream>>>(indptr, srcs, N);

    int gNH = (N*NHEADS+255)/256;
    int gRow = (N+63)/64;
    int gWave = ((size_t)N*64+255)/256;

    // fc0
    k_fc0<<<(N*16+255)/256,256,0,stream>>>(x, W0, b0, nfA, N);

    // GAT1: 16 -> H x 32
    k_gemm<16,0,1><<<dim3(gRow,320/64),256,0,stream>>>(nfA, Wc1, nullptr, hf, N, 320);
    k_attn<32><<<gNH,256,0,stream>>>(hf, as1, ad1, es, ed, N);
    k_stats<<<gNH,256,0,stream>>>(indptr, srcs, es, ed, wbuf, N);
    k_agg<32><<<gWave,256,0,stream>>>(indptr, srcs, wbuf, hf, bc1, nfB, N);

    // GAT2: 32 -> H x 64
    k_gemm<32,0,1><<<dim3(gRow,640/64),256,0,stream>>>(nfB, Wc2, nullptr, hf, N, 640);
    k_attn<64><<<gNH,256,0,stream>>>(hf, as2, ad2, es, ed, N);
    k_stats<<<gNH,256,0,stream>>>(indptr, srcs, es, ed, wbuf, N);
    k_agg<64><<<gWave,256,0,stream>>>(indptr, srcs, wbuf, hf, bc2, nfA, N);

    // GAT3: 64 -> H x 128
    k_gemm<64,0,1><<<dim3(gRow,1280/64),256,0,stream>>>(nfA, Wc3, nullptr, hf, N, 1280);
    k_attn<128><<<gNH,256,0,stream>>>(hf, as3, ad3, es, ed, N);
    k_stats<<<gNH,256,0,stream>>>(indptr, srcs, es, ed, wbuf, N);
    k_agg<128><<<gWave,256,0,stream>>>(indptr, srcs, wbuf, hf, bc3, nfB, N);

    // fc1: [N,128]@[128,256] + bias + ELU (f32 out)
    k_gemm<128,1,0><<<dim3(gRow,256/64),256,0,stream>>>(nfB, W1, b1, nfA, N, 256);
    // head
    k_head<<<(N+7)/8,256,0,stream>>>(nfA, W2, b2, out, N);
}

// Round 10
// 347.273 us; speedup vs baseline: 1.2115x; 1.1239x over previous
//
#include <hip/hip_runtime.h>
#include <hip/hip_bf16.h>
#include <math.h>

#define NHEADS 10

typedef unsigned short ushort_t;
typedef unsigned int uint_t;

__device__ __forceinline__ float bu2f(ushort_t u){ return __uint_as_float(((uint_t)u)<<16); }
__device__ __forceinline__ ushort_t f2bu(float f){
    uint_t b = __float_as_uint(f);
    return (ushort_t)((b + 0x7FFFu + ((b>>16)&1u)) >> 16);   // RNE
}

// ---------------- CSR build ----------------
__global__ void k_count(const int* eidx, int E, int N, int* cnt){
    int e = blockIdx.x*blockDim.x + threadIdx.x;
    int ET = E + N;
    if(e >= ET) return;
    int d = (e < E) ? eidx[E + e] : (e - E);
    atomicAdd(&cnt[d], 1);
}

__global__ void k_scan(int* cnt, int N, int ET, int* indptr){
    __shared__ int lds[1024];
    int t = threadIdx.x;
    int chunk = (N + 1023)/1024;
    int base = t*chunk;
    int s = 0;
    for(int i=0;i<chunk;i++){ int idx=base+i; if(idx<N) s += cnt[idx]; }
    lds[t]=s;
    __syncthreads();
    for(int off=1; off<1024; off<<=1){
        int v = (t>=off)? lds[t-off] : 0;
        __syncthreads();
        lds[t]+=v;
        __syncthreads();
    }
    int run = lds[t]-s;
    for(int i=0;i<chunk;i++){
        int idx=base+i;
        if(idx<N){
            int c = cnt[idx];
            indptr[idx]=run;
            cnt[idx]=run;
            run += c;
        }
    }
    if(t==0) indptr[N]=ET;
}

__global__ void k_fill(const int* eidx, int E, int N, int* cursor, int* srcs){
    int e = blockIdx.x*blockDim.x + threadIdx.x;
    int ET = E + N;
    if(e >= ET) return;
    int s, d;
    if(e < E){ s = eidx[e]; d = eidx[E+e]; } else { s = e-E; d = e-E; }
    int pos = atomicAdd(&cursor[d], 1);
    srcs[pos] = s;
}

// wave-parallel bitonic sort of each node's src segment (1 wave / node)
__global__ void k_sortw(const int* indptr, int* srcs, int N){
    int wid  = (blockIdx.x*blockDim.x + threadIdx.x) >> 6;
    int lane = threadIdx.x & 63;
    if(wid >= N) return;
    int p0 = indptr[wid], p1 = indptr[wid+1];
    int deg = p1 - p0;
    if(deg <= 1) return;
    if(deg <= 64){
        int v = (lane < deg) ? srcs[p0+lane] : 0x7FFFFFFF;
        #pragma unroll
        for(int k=2; k<=64; k<<=1){
            #pragma unroll
            for(int j=k>>1; j>0; j>>=1){
                int partner = __shfl_xor(v, j, 64);
                bool dir   = ((lane & k) == 0);
                bool small = ((lane & j) == 0);
                int mn = min(v, partner), mx = max(v, partner);
                v = (dir == small) ? mn : mx;
            }
        }
        if(lane < deg) srcs[p0+lane] = v;
    } else if(lane == 0){               // safety fallback, statistically never
        for(int i=p0+1;i<p1;i++){
            int v2 = srcs[i]; int j=i-1;
            while(j>=p0 && srcs[j]>v2){ srcs[j+1]=srcs[j]; j--; }
            srcs[j+1]=v2;
        }
    }
}

// ---------------- fc0: [N,24]@[24,16]+b, ELU ----------------
__global__ void k_fc0(const float* x, const float* W0, const float* b0, float* out, int N){
    int idx = blockIdx.x*blockDim.x+threadIdx.x;
    if(idx >= N*16) return;
    int n = idx>>4, c = idx&15;
    float acc = b0[c];
    #pragma unroll
    for(int k=0;k<24;k++) acc += x[n*24+k] * W0[k*16+c];
    out[idx] = acc>0.f ? acc : expm1f(acc);
}

// ---------------- tiled GEMM: C[N,HC] = A[N,K] @ B[K,HC] ----------------
// 64x64 tile / block, 256 threads, 4x4 micro-tile. unroll 8 (full unroll spilled: R3).
template<int K, int EPI, int OUTBF16>
__global__ void __launch_bounds__(256, 2)
k_gemm(const float* __restrict__ A, const float* __restrict__ B,
       const float* __restrict__ bias, void* __restrict__ Cmat,
       int N, int HC){
    constexpr int KC = (K > 64) ? 64 : K;
    __shared__ float As[64][K+1];
    __shared__ float Bs[KC][68];

    int t = threadIdx.x;
    int row0 = blockIdx.x*64;
    int col0 = blockIdx.y*64;

    for(int i=t; i<64*K; i+=256){
        int r = i/K, k = i%K;
        int row = row0 + r;
        As[r][k] = (row < N) ? A[(size_t)row*K + k] : 0.f;
    }

    int tr = t>>4, tc = t&15;
    int r0 = tr*4, c0 = tc*4;

    float acc[4][4];
    #pragma unroll
    for(int i=0;i<4;i++)
        #pragma unroll
        for(int j=0;j<4;j++) acc[i][j]=0.f;

    for(int kb=0; kb<K; kb+=KC){
        __syncthreads();
        for(int i=t; i<KC*64; i+=256){
            int k = i>>6, c = i&63;
            Bs[k][c] = B[(size_t)(kb+k)*HC + col0 + c];
        }
        __syncthreads();
        #pragma unroll 8
        for(int k=0;k<KC;k++){
            float4 b = *(const float4*)&Bs[k][c0];
            float a0 = As[r0+0][kb+k];
            float a1 = As[r0+1][kb+k];
            float a2 = As[r0+2][kb+k];
            float a3 = As[r0+3][kb+k];
            acc[0][0] += a0*b.x; acc[0][1] += a0*b.y; acc[0][2] += a0*b.z; acc[0][3] += a0*b.w;
            acc[1][0] += a1*b.x; acc[1][1] += a1*b.y; acc[1][2] += a1*b.z; acc[1][3] += a1*b.w;
            acc[2][0] += a2*b.x; acc[2][1] += a2*b.y; acc[2][2] += a2*b.z; acc[2][3] += a2*b.w;
            acc[3][0] += a3*b.x; acc[3][1] += a3*b.y; acc[3][2] += a3*b.z; acc[3][3] += a3*b.w;
        }
    }

    #pragma unroll
    for(int i=0;i<4;i++){
        int row = row0 + r0 + i;
        if(row >= N) continue;
        float4 v;
        v.x = acc[i][0]; v.y = acc[i][1]; v.z = acc[i][2]; v.w = acc[i][3];
        if(EPI){
            v.x += bias[col0+c0+0]; v.y += bias[col0+c0+1];
            v.z += bias[col0+c0+2]; v.w += bias[col0+c0+3];
            v.x = v.x>0.f? v.x : expm1f(v.x);
            v.y = v.y>0.f? v.y : expm1f(v.y);
            v.z = v.z>0.f? v.z : expm1f(v.z);
            v.w = v.w>0.f? v.w : expm1f(v.w);
        }
        if(OUTBF16){
            ushort4 u;
            u.x = f2bu(v.x); u.y = f2bu(v.y); u.z = f2bu(v.z); u.w = f2bu(v.w);
            *(ushort4*)&((ushort_t*)Cmat)[(size_t)row*HC + col0 + c0] = u;
        } else {
            *(float4*)&((float*)Cmat)[(size_t)row*HC + col0 + c0] = v;
        }
    }
}

// ---------------- attention logits per (n,h), bf16 hf ----------------
template<int C>
__global__ void k_attn(const ushort_t* hf, const float* a_s, const float* a_d,
                       float* es, float* ed, int N){
    int idx = blockIdx.x*blockDim.x+threadIdx.x;
    if(idx >= N*NHEADS) return;
    int n = idx/NHEADS, h = idx%NHEADS;
    const uint4* hp = reinterpret_cast<const uint4*>(hf + (size_t)n*NHEADS*C + h*C);
    float s=0.f, d=0.f;
    #pragma unroll
    for(int cb=0; cb<C/8; cb++){
        uint4 q = hp[cb];
        uint_t uu[4] = {q.x, q.y, q.z, q.w};
        #pragma unroll
        for(int j=0;j<4;j++){
            float f0 = __uint_as_float(uu[j]<<16);
            float f1 = __uint_as_float(uu[j] & 0xFFFF0000u);
            int c = cb*8 + j*2;
            s += f0*a_s[h*C+c]   + f1*a_s[h*C+c+1];
            d += f0*a_d[h*C+c]   + f1*a_d[h*C+c+1];
        }
    }
    es[idx]=s; ed[idx]=d;
}

// ---------------- fused softmax + aggregation: one wave per node, 4 nodes/block ----------------
// phase1: leaky logits -> LDS (lanes as 6 edges x 10 heads)
// phase2: per-head online max+den (10 lanes, serial LDS scan, order = edge order)
// phase3: normalize weights in LDS
// phase4: R9-style gather (TPN channel-groups x EG edge-groups, uint4 loads), weights from LDS
// deg>64 handled by block-uniform chunking (recompute logits per chunk) -- statistically never taken.
template<int C>
__global__ void __launch_bounds__(256, 4)
k_fused(const int* __restrict__ indptr, const int* __restrict__ srcs,
        const float* __restrict__ es, const float* __restrict__ ed,
        const ushort_t* __restrict__ hf, const float* __restrict__ bc,
        float* __restrict__ out, int N)
{
    __shared__ float wlds[4][64*NHEADS];   // 2.56 KB per wave
    __shared__ float stat[4][2*NHEADS];
    __shared__ int   degs[4];
    int wslot = threadIdx.x >> 6;
    int lane  = threadIdx.x & 63;
    int n = (blockIdx.x << 2) + wslot;
    bool valid = (n < N);
    int p0 = 0, deg = 0;
    if(valid){ p0 = indptr[n]; deg = indptr[n+1] - p0; }
    if(lane == 0) degs[wslot] = deg;
    __syncthreads();
    int maxdeg = max(max(degs[0],degs[1]), max(degs[2],degs[3]));
    int nch = (maxdeg + 63) >> 6;          // block-uniform chunk count (==1 in practice)
    float* wl = wlds[wslot];

    int e6 = lane/10, h6 = lane%10;        // 60 active lanes in phases 1-3
    float edv = (valid && lane < 60) ? ed[n*NHEADS + h6] : 0.f;

    // ---- pass A: per-head online max + denominator ----
    float m = -1e30f, den = 0.f;           // meaningful on lanes < 10
    for(int c = 0; c < nch; c++){
        int base = c << 6;
        int lim = deg - base; if(lim > 64) lim = 64;
        if(valid && lane < 60){
            for(int i = e6; i < lim; i += 6){
                float v = es[(size_t)srcs[p0+base+i]*NHEADS + h6] + edv;
                v = (v >= 0.f) ? v : 0.2f*v;
                wl[i*NHEADS + h6] = v;
            }
        }
        __syncthreads();
        if(valid && lane < NHEADS){
            for(int i = 0; i < lim; i++){
                float v = wl[i*NHEADS + lane];
                float nm = fmaxf(m, v);
                den = den*expf(m-nm) + expf(v-nm);
                m = nm;
            }
        }
        __syncthreads();
    }
    if(valid && lane < NHEADS){
        stat[wslot][lane] = m;
        stat[wslot][NHEADS+lane] = 1.f/(den + 1e-16f);
    }
    __syncthreads();

    // ---- pass B: normalize weights + gather ----
    constexpr int TPN = C/8;
    constexpr int EG  = 64/TPN;
    int local = lane % TPN, eg = lane / TPN;
    int c8 = local*8;
    float acc[8];
    #pragma unroll
    for(int i=0;i<8;i++) acc[i]=0.f;

    for(int c = 0; c < nch; c++){
        int base = c << 6;
        int lim = deg - base; if(lim > 64) lim = 64;
        if(nch > 1){                        // refill logits (uniform branch)
            if(valid && lane < 60){
                for(int i = e6; i < lim; i += 6){
                    float v = es[(size_t)srcs[p0+base+i]*NHEADS + h6] + edv;
                    v = (v >= 0.f) ? v : 0.2f*v;
                    wl[i*NHEADS + h6] = v;
                }
            }
            __syncthreads();
        }
        if(valid && lane < 60){
            float mm = stat[wslot][h6], dv = stat[wslot][NHEADS+h6];
            for(int i = e6; i < lim; i += 6)
                wl[i*NHEADS + h6] = expf(wl[i*NHEADS + h6] - mm) * dv;
        }
        __syncthreads();
        if(valid){
            for(int i = eg; i < lim; i += EG){
                int s = srcs[p0+base+i];
                const ushort_t* hp = hf + (size_t)s*NHEADS*C + c8;
                const float* wp = &wl[i*NHEADS];
                #pragma unroll
                for(int h=0;h<NHEADS;h++){
                    uint4 q = *(const uint4*)(hp + h*C);
                    float w = wp[h];
                    acc[0] += w * __uint_as_float(q.x<<16);
                    acc[1] += w * __uint_as_float(q.x & 0xFFFF0000u);
                    acc[2] += w * __uint_as_float(q.y<<16);
                    acc[3] += w * __uint_as_float(q.y & 0xFFFF0000u);
                    acc[4] += w * __uint_as_float(q.z<<16);
                    acc[5] += w * __uint_as_float(q.z & 0xFFFF0000u);
                    acc[6] += w * __uint_as_float(q.w<<16);
                    acc[7] += w * __uint_as_float(q.w & 0xFFFF0000u);
                }
            }
        }
        __syncthreads();
    }

    // fold edge groups
    #pragma unroll
    for(int s = TPN; s < 64; s <<= 1){
        #pragma unroll
        for(int i=0;i<8;i++) acc[i] += __shfl_xor(acc[i], s, 64);
    }
    if(valid && eg == 0){
        float4 v0, v1;
        #pragma unroll
        for(int i=0;i<8;i++){
            float v = acc[i]*(1.f/NHEADS) + bc[c8+i];
            v = v>0.f ? v : expm1f(v);
            if(i<4) ((float*)&v0)[i] = v; else ((float*)&v1)[i-4] = v;
        }
        *(float4*)&out[(size_t)n*C + c8]     = v0;
        *(float4*)&out[(size_t)n*C + c8 + 4] = v1;
    }
}

// ---------------- head: logits 256->24 + log_softmax ----------------
__global__ void k_head(const float* hin, const float* W2, const float* b2v, float* out, int N){
    int grp  = threadIdx.x/32;
    int lane = threadIdx.x%32;
    int n = blockIdx.x*8 + grp;
    if(n>=N) return;
    float acc = -1e30f;
    if(lane < 24){
        acc = b2v[lane];
        for(int k=0;k<256;k++) acc += hin[n*256+k]*W2[k*24+lane];
    }
    float mx = acc;
    for(int off=16; off; off>>=1) mx = fmaxf(mx, __shfl_xor(mx, off, 32));
    float ex = (lane<24)? expf(acc-mx) : 0.f;
    float sm = ex;
    for(int off=16; off; off>>=1) sm += __shfl_xor(sm, off, 32);
    if(lane<24) out[n*24+lane] = acc - mx - logf(sm);
}

extern "C" void kernel_launch(void* const* d_in, const int* in_sizes, int n_in,
                              void* d_out, int out_size, void* d_ws, size_t ws_size,
                              hipStream_t stream) {
    const float* x   = (const float*)d_in[0];
    const int*  eidx = (const int*)d_in[1];
    const float* W0 = (const float*)d_in[3];  const float* b0 = (const float*)d_in[4];
    const float* Wc1= (const float*)d_in[5];  const float* as1= (const float*)d_in[6];
    const float* ad1= (const float*)d_in[7];  const float* bc1= (const float*)d_in[8];
    const float* Wc2= (const float*)d_in[9];  const float* as2= (const float*)d_in[10];
    const float* ad2= (const float*)d_in[11]; const float* bc2= (const float*)d_in[12];
    const float* Wc3= (const float*)d_in[13]; const float* as3= (const float*)d_in[14];
    const float* ad3= (const float*)d_in[15]; const float* bc3= (const float*)d_in[16];
    const float* W1 = (const float*)d_in[17]; const float* b1 = (const float*)d_in[18];
    const float* W2 = (const float*)d_in[19]; const float* b2 = (const float*)d_in[20];
    float* out = (float*)d_out;

    const int N  = in_sizes[0]/24;
    const int E  = in_sizes[1]/2;
    const int ET = E + N;

    char* w = (char*)d_ws;
    size_t off = 0;
    auto alloc = [&](size_t bytes)->void* {
        void* p = w + off;
        off = (off + bytes + 255) & ~(size_t)255;
        return p;
    };
    int*   cnt    = (int*)  alloc((size_t)N*4);
    int*   indptr = (int*)  alloc((size_t)(N+1)*4);
    int*   srcs   = (int*)  alloc((size_t)ET*4);
    float* es     = (float*)alloc((size_t)N*NHEADS*4);
    float* ed     = (float*)alloc((size_t)N*NHEADS*4);
    float* nfA    = (float*)alloc((size_t)N*256*4);
    float* nfB    = (float*)alloc((size_t)N*256*4);
    ushort_t* hf  = (ushort_t*)alloc((size_t)N*1280*2);

    // CSR by dst
    hipMemsetAsync(cnt, 0, (size_t)N*4, stream);
    int gE = (ET+255)/256;
    k_count<<<gE,256,0,stream>>>(eidx, E, N, cnt);
    k_scan <<<1,1024,0,stream>>>(cnt, N, ET, indptr);
    k_fill <<<gE,256,0,stream>>>(eidx, E, N, cnt, srcs);
    k_sortw<<<((size_t)N*64+255)/256,256,0,stream>>>(indptr, srcs, N);

    int gNH = (N*NHEADS+255)/256;
    int gRow = (N+63)/64;
    int gNode = (N+3)/4;

    // fc0
    k_fc0<<<(N*16+255)/256,256,0,stream>>>(x, W0, b0, nfA, N);

    // GAT1: 16 -> H x 32
    k_gemm<16,0,1><<<dim3(gRow,320/64),256,0,stream>>>(nfA, Wc1, nullptr, hf, N, 320);
    k_attn<32><<<gNH,256,0,stream>>>(hf, as1, ad1, es, ed, N);
    k_fused<32><<<gNode,256,0,stream>>>(indptr, srcs, es, ed, hf, bc1, nfB, N);

    // GAT2: 32 -> H x 64
    k_gemm<32,0,1><<<dim3(gRow,640/64),256,0,stream>>>(nfB, Wc2, nullptr, hf, N, 640);
    k_attn<64><<<gNH,256,0,stream>>>(hf, as2, ad2, es, ed, N);
    k_fused<64><<<gNode,256,0,stream>>>(indptr, srcs, es, ed, hf, bc2, nfA, N);

    // GAT3: 64 -> H x 128
    k_gemm<64,0,1><<<dim3(gRow,1280/64),256,0,stream>>>(nfA, Wc3, nullptr, hf, N, 1280);
    k_attn<128><<<gNH,256,0,stream>>>(hf, as3, ad3, es, ed, N);
    k_fused<128><<<gNode,256,0,stream>>>(indptr, srcs, es, ed, hf, bc3, nfB, N);

    // fc1: [N,128]@[128,256] + bias + ELU (f32 out)
    k_gemm<128,1,0><<<dim3(gRow,256/64),256,0,stream>>>(nfB, W1, b1, nfA, N, 256);
    // head
    k_head<<<(N+7)/8,256,0,stream>>>(nfA, W2, b2, out, N);
}

// Round 11
// 305.069 us; speedup vs baseline: 1.3791x; 1.1383x over previous
//
#include <hip/hip_runtime.h>
#include <hip/hip_bf16.h>
#include <math.h>

#define NHEADS 10

typedef unsigned short ushort_t;
typedef unsigned int uint_t;

typedef __attribute__((ext_vector_type(4))) float f32x4;
typedef __attribute__((ext_vector_type(8))) short short8;

__device__ __forceinline__ float bu2f(ushort_t u){ return __uint_as_float(((uint_t)u)<<16); }
__device__ __forceinline__ ushort_t f2bu(float f){
    uint_t b = __float_as_uint(f);
    return (ushort_t)((b + 0x7FFFu + ((b>>16)&1u)) >> 16);   // RNE
}

// ---------------- CSR build ----------------
__global__ void k_count(const int* eidx, int E, int N, int* cnt){
    int e = blockIdx.x*blockDim.x + threadIdx.x;
    int ET = E + N;
    if(e >= ET) return;
    int d = (e < E) ? eidx[E + e] : (e - E);
    atomicAdd(&cnt[d], 1);
}

__global__ void k_scan(int* cnt, int N, int ET, int* indptr){
    __shared__ int lds[1024];
    int t = threadIdx.x;
    int chunk = (N + 1023)/1024;
    int base = t*chunk;
    int s = 0;
    for(int i=0;i<chunk;i++){ int idx=base+i; if(idx<N) s += cnt[idx]; }
    lds[t]=s;
    __syncthreads();
    for(int off=1; off<1024; off<<=1){
        int v = (t>=off)? lds[t-off] : 0;
        __syncthreads();
        lds[t]+=v;
        __syncthreads();
    }
    int run = lds[t]-s;
    for(int i=0;i<chunk;i++){
        int idx=base+i;
        if(idx<N){
            int c = cnt[idx];
            indptr[idx]=run;
            cnt[idx]=run;
            run += c;
        }
    }
    if(t==0) indptr[N]=ET;
}

__global__ void k_fill(const int* eidx, int E, int N, int* cursor, int* srcs){
    int e = blockIdx.x*blockDim.x + threadIdx.x;
    int ET = E + N;
    if(e >= ET) return;
    int s, d;
    if(e < E){ s = eidx[e]; d = eidx[E+e]; } else { s = e-E; d = e-E; }
    int pos = atomicAdd(&cursor[d], 1);
    srcs[pos] = s;
}

// wave-parallel bitonic sort of each node's src segment (1 wave / node)
__global__ void k_sortw(const int* indptr, int* srcs, int N){
    int wid  = (blockIdx.x*blockDim.x + threadIdx.x) >> 6;
    int lane = threadIdx.x & 63;
    if(wid >= N) return;
    int p0 = indptr[wid], p1 = indptr[wid+1];
    int deg = p1 - p0;
    if(deg <= 1) return;
    if(deg <= 64){
        int v = (lane < deg) ? srcs[p0+lane] : 0x7FFFFFFF;
        #pragma unroll
        for(int k=2; k<=64; k<<=1){
            #pragma unroll
            for(int j=k>>1; j>0; j>>=1){
                int partner = __shfl_xor(v, j, 64);
                bool dir   = ((lane & k) == 0);
                bool small = ((lane & j) == 0);
                int mn = min(v, partner), mx = max(v, partner);
                v = (dir == small) ? mn : mx;
            }
        }
        if(lane < deg) srcs[p0+lane] = v;
    } else if(lane == 0){               // safety fallback, statistically never
        for(int i=p0+1;i<p1;i++){
            int v2 = srcs[i]; int j=i-1;
            while(j>=p0 && srcs[j]>v2){ srcs[j+1]=srcs[j]; j--; }
            srcs[j+1]=v2;
        }
    }
}

// ---------------- fc0: [N,24]@[24,16]+b, ELU ----------------
__global__ void k_fc0(const float* x, const float* W0, const float* b0, float* out, int N){
    int idx = blockIdx.x*blockDim.x+threadIdx.x;
    if(idx >= N*16) return;
    int n = idx>>4, c = idx&15;
    float acc = b0[c];
    #pragma unroll
    for(int k=0;k<24;k++) acc += x[n*24+k] * W0[k*16+c];
    out[idx] = acc>0.f ? acc : expm1f(acc);
}

// ---------------- MFMA GEMM: C[N,HC] = A[N,K] @ B[K,HC] (bf16 inputs, f32 accum) ----------------
// 64x64 tile / block, 4 waves; each wave: 16 rows x 64 cols = 4 x mfma_f32_16x16x32_bf16.
// A fragment: row = lane&15, k = (lane>>4)*8+j.  B staged transposed so frag reads are b128.
// C/D: col = lane&15, row = (lane>>4)*4 + reg   [guide §3, HW-verified m89].
template<int K, int EPI, int OUTBF16>
__global__ void __launch_bounds__(256, 4)
k_gemm(const float* __restrict__ A, const float* __restrict__ B,
       const float* __restrict__ bias, void* __restrict__ Cmat,
       int N, int HC){
    __shared__ ushort_t As [64][40];   // row stride 80 B (16B-aligned frag reads, ~2-way banks)
    __shared__ ushort_t BsT[64][40];   // BsT[col][k]

    int t = threadIdx.x;
    int w = t >> 6, lane = t & 63;
    int lr = lane & 15, lk = lane >> 4;
    int row0 = blockIdx.x*64, col0 = blockIdx.y*64;

    f32x4 acc[4];
    #pragma unroll
    for(int f=0; f<4; f++) acc[f] = (f32x4){0.f,0.f,0.f,0.f};

    for(int kb = 0; kb < K; kb += 32){
        __syncthreads();
        // stage A tile [64 rows][32 k] -> bf16 (zero-pad k>=K and row>=N)
        for(int idx = t; idx < 512; idx += 256){
            int r = idx >> 3, kq = idx & 7;
            int row = row0 + r;
            float4 v = {0.f,0.f,0.f,0.f};
            if(row < N && (kb + kq*4) < K)
                v = *(const float4*)&A[(size_t)row*K + kb + kq*4];
            ushort4 u; u.x=f2bu(v.x); u.y=f2bu(v.y); u.z=f2bu(v.z); u.w=f2bu(v.w);
            *(ushort4*)&As[r][kq*4] = u;
        }
        // stage B^T tile: BsT[c][k] = B[kb+k][col0+c]
        for(int idx = t; idx < 2048; idx += 256){
            int k = idx >> 6, c = idx & 63;
            float v = (kb + k < K) ? B[(size_t)(kb+k)*HC + col0 + c] : 0.f;
            BsT[c][k] = f2bu(v);
        }
        __syncthreads();
        short8 af = *(const short8*)&As[w*16 + lr][lk*8];
        #pragma unroll
        for(int f=0; f<4; f++){
            short8 bf = *(const short8*)&BsT[f*16 + lr][lk*8];
            acc[f] = __builtin_amdgcn_mfma_f32_16x16x32_bf16(af, bf, acc[f], 0, 0, 0);
        }
    }

    #pragma unroll
    for(int f=0; f<4; f++){
        #pragma unroll
        for(int j=0; j<4; j++){
            int row = row0 + w*16 + lk*4 + j;
            if(row >= N) continue;
            int col = col0 + f*16 + lr;
            float v = acc[f][j];
            if(EPI){
                v += bias[col];
                v = v>0.f ? v : expm1f(v);
            }
            if(OUTBF16) ((ushort_t*)Cmat)[(size_t)row*HC + col] = f2bu(v);
            else        ((float*)Cmat)[(size_t)row*HC + col] = v;
        }
    }
}

// ---------------- attention logits per (n,h), bf16 hf ----------------
template<int C>
__global__ void k_attn(const ushort_t* hf, const float* a_s, const float* a_d,
                       float* es, float* ed, int N){
    int idx = blockIdx.x*blockDim.x+threadIdx.x;
    if(idx >= N*NHEADS) return;
    int n = idx/NHEADS, h = idx%NHEADS;
    const uint4* hp = reinterpret_cast<const uint4*>(hf + (size_t)n*NHEADS*C + h*C);
    float s=0.f, d=0.f;
    #pragma unroll
    for(int cb=0; cb<C/8; cb++){
        uint4 q = hp[cb];
        uint_t uu[4] = {q.x, q.y, q.z, q.w};
        #pragma unroll
        for(int j=0;j<4;j++){
            float f0 = __uint_as_float(uu[j]<<16);
            float f1 = __uint_as_float(uu[j] & 0xFFFF0000u);
            int c = cb*8 + j*2;
            s += f0*a_s[h*C+c]   + f1*a_s[h*C+c+1];
            d += f0*a_d[h*C+c]   + f1*a_d[h*C+c+1];
        }
    }
    es[idx]=s; ed[idx]=d;
}

// ---------------- fused softmax + aggregation (no-max-subtraction variant) ----------------
// alpha = exp(e)/sum exp(e): exp(m) cancels vs reference; e clamped at 60 (never active with
// this data's O(1) logits) to guarantee no overflow. One expf per (edge,head), serial phase
// is adds only, 2 barriers per chunk.
template<int C>
__global__ void __launch_bounds__(256, 4)
k_fused(const int* __restrict__ indptr, const int* __restrict__ srcs,
        const float* __restrict__ es, const float* __restrict__ ed,
        const ushort_t* __restrict__ hf, const float* __restrict__ bc,
        float* __restrict__ out, int N)
{
    __shared__ float wlds[4][64*NHEADS];
    __shared__ float stat[4][NHEADS];      // 1/den per head
    __shared__ int   degs[4];
    int wslot = threadIdx.x >> 6;
    int lane  = threadIdx.x & 63;
    int n = (blockIdx.x << 2) + wslot;
    bool valid = (n < N);
    int p0 = 0, deg = 0;
    if(valid){ p0 = indptr[n]; deg = indptr[n+1] - p0; }
    if(lane == 0) degs[wslot] = deg;
    __syncthreads();
    int maxdeg = max(max(degs[0],degs[1]), max(degs[2],degs[3]));
    int nch = (maxdeg + 63) >> 6;          // block-uniform chunk count (==1 in practice)
    float* wl = wlds[wslot];

    int e6 = lane/10, h6 = lane%10;        // 60 active lanes in fill
    float edv = (valid && lane < 60) ? ed[n*NHEADS + h6] : 0.f;

    // ---- pass A: w = exp(leaky(e)) into LDS; serial per-head den (adds only) ----
    float den = 0.f;                        // meaningful on lanes < 10
    for(int c = 0; c < nch; c++){
        int base = c << 6;
        int lim = deg - base; if(lim > 64) lim = 64;
        if(valid && lane < 60){
            for(int i = e6; i < lim; i += 6){
                float v = es[(size_t)srcs[p0+base+i]*NHEADS + h6] + edv;
                v = (v >= 0.f) ? v : 0.2f*v;
                wl[i*NHEADS + h6] = expf(fminf(v, 60.f));
            }
        }
        __syncthreads();
        if(valid && lane < NHEADS){
            for(int i = 0; i < lim; i++) den += wl[i*NHEADS + lane];
        }
        if(nch > 1) __syncthreads();       // wl about to be overwritten next chunk
    }
    if(valid && lane < NHEADS) stat[wslot][lane] = 1.f/(den + 1e-30f);
    __syncthreads();

    // ---- pass B: gather, weights = wl * dinv (dinv hoisted to registers) ----
    constexpr int TPN = C/8;
    constexpr int EG  = 64/TPN;
    int local = lane % TPN, eg = lane / TPN;
    int c8 = local*8;
    float dinv_r[NHEADS];
    #pragma unroll
    for(int h=0; h<NHEADS; h++) dinv_r[h] = stat[wslot][h];
    float acc[8];
    #pragma unroll
    for(int i=0;i<8;i++) acc[i]=0.f;

    for(int c = 0; c < nch; c++){
        int base = c << 6;
        int lim = deg - base; if(lim > 64) lim = 64;
        if(nch > 1){                        // refill (uniform branch; never in practice)
            if(valid && lane < 60){
                for(int i = e6; i < lim; i += 6){
                    float v = es[(size_t)srcs[p0+base+i]*NHEADS + h6] + edv;
                    v = (v >= 0.f) ? v : 0.2f*v;
                    wl[i*NHEADS + h6] = expf(fminf(v, 60.f));
                }
            }
            __syncthreads();
        }
        if(valid){
            for(int i = eg; i < lim; i += EG){
                int s = srcs[p0+base+i];
                const ushort_t* hp = hf + (size_t)s*NHEADS*C + c8;
                const float* wp = &wl[i*NHEADS];
                #pragma unroll
                for(int h=0;h<NHEADS;h++){
                    uint4 q = *(const uint4*)(hp + h*C);
                    float wd = wp[h]*dinv_r[h];
                    acc[0] += wd * __uint_as_float(q.x<<16);
                    acc[1] += wd * __uint_as_float(q.x & 0xFFFF0000u);
                    acc[2] += wd * __uint_as_float(q.y<<16);
                    acc[3] += wd * __uint_as_float(q.y & 0xFFFF0000u);
                    acc[4] += wd * __uint_as_float(q.z<<16);
                    acc[5] += wd * __uint_as_float(q.z & 0xFFFF0000u);
                    acc[6] += wd * __uint_as_float(q.w<<16);
                    acc[7] += wd * __uint_as_float(q.w & 0xFFFF0000u);
                }
            }
        }
        if(nch > 1) __syncthreads();
    }

    // fold edge groups
    #pragma unroll
    for(int s = TPN; s < 64; s <<= 1){
        #pragma unroll
        for(int i=0;i<8;i++) acc[i] += __shfl_xor(acc[i], s, 64);
    }
    if(valid && eg == 0){
        float4 v0, v1;
        #pragma unroll
        for(int i=0;i<8;i++){
            float v = acc[i]*(1.f/NHEADS) + bc[c8+i];
            v = v>0.f ? v : expm1f(v);
            if(i<4) ((float*)&v0)[i] = v; else ((float*)&v1)[i-4] = v;
        }
        *(float4*)&out[(size_t)n*C + c8]     = v0;
        *(float4*)&out[(size_t)n*C + c8 + 4] = v1;
    }
}

// ---------------- head: logits 256->24 + log_softmax ----------------
__global__ void k_head(const float* hin, const float* W2, const float* b2v, float* out, int N){
    int grp  = threadIdx.x/32;
    int lane = threadIdx.x%32;
    int n = blockIdx.x*8 + grp;
    if(n>=N) return;
    float acc = -1e30f;
    if(lane < 24){
        acc = b2v[lane];
        for(int k=0;k<256;k++) acc += hin[n*256+k]*W2[k*24+lane];
    }
    float mx = acc;
    for(int off=16; off; off>>=1) mx = fmaxf(mx, __shfl_xor(mx, off, 32));
    float ex = (lane<24)? expf(acc-mx) : 0.f;
    float sm = ex;
    for(int off=16; off; off>>=1) sm += __shfl_xor(sm, off, 32);
    if(lane<24) out[n*24+lane] = acc - mx - logf(sm);
}

extern "C" void kernel_launch(void* const* d_in, const int* in_sizes, int n_in,
                              void* d_out, int out_size, void* d_ws, size_t ws_size,
                              hipStream_t stream) {
    const float* x   = (const float*)d_in[0];
    const int*  eidx = (const int*)d_in[1];
    const float* W0 = (const float*)d_in[3];  const float* b0 = (const float*)d_in[4];
    const float* Wc1= (const float*)d_in[5];  const float* as1= (const float*)d_in[6];
    const float* ad1= (const float*)d_in[7];  const float* bc1= (const float*)d_in[8];
    const float* Wc2= (const float*)d_in[9];  const float* as2= (const float*)d_in[10];
    const float* ad2= (const float*)d_in[11]; const float* bc2= (const float*)d_in[12];
    const float* Wc3= (const float*)d_in[13]; const float* as3= (const float*)d_in[14];
    const float* ad3= (const float*)d_in[15]; const float* bc3= (const float*)d_in[16];
    const float* W1 = (const float*)d_in[17]; const float* b1 = (const float*)d_in[18];
    const float* W2 = (const float*)d_in[19]; const float* b2 = (const float*)d_in[20];
    float* out = (float*)d_out;

    const int N  = in_sizes[0]/24;
    const int E  = in_sizes[1]/2;
    const int ET = E + N;

    char* w = (char*)d_ws;
    size_t off = 0;
    auto alloc = [&](size_t bytes)->void* {
        void* p = w + off;
        off = (off + bytes + 255) & ~(size_t)255;
        return p;
    };
    int*   cnt    = (int*)  alloc((size_t)N*4);
    int*   indptr = (int*)  alloc((size_t)(N+1)*4);
    int*   srcs   = (int*)  alloc((size_t)ET*4);
    float* es     = (float*)alloc((size_t)N*NHEADS*4);
    float* ed     = (float*)alloc((size_t)N*NHEADS*4);
    float* nfA    = (float*)alloc((size_t)N*256*4);
    float* nfB    = (float*)alloc((size_t)N*256*4);
    ushort_t* hf  = (ushort_t*)alloc((size_t)N*1280*2);

    // CSR by dst
    hipMemsetAsync(cnt, 0, (size_t)N*4, stream);
    int gE = (ET+255)/256;
    k_count<<<gE,256,0,stream>>>(eidx, E, N, cnt);
    k_scan <<<1,1024,0,stream>>>(cnt, N, ET, indptr);
    k_fill <<<gE,256,0,stream>>>(eidx, E, N, cnt, srcs);
    k_sortw<<<((size_t)N*64+255)/256,256,0,stream>>>(indptr, srcs, N);

    int gNH = (N*NHEADS+255)/256;
    int gRow = (N+63)/64;
    int gNode = (N+3)/4;

    // fc0
    k_fc0<<<(N*16+255)/256,256,0,stream>>>(x, W0, b0, nfA, N);

    // GAT1: 16 -> H x 32
    k_gemm<16,0,1><<<dim3(gRow,320/64),256,0,stream>>>(nfA, Wc1, nullptr, hf, N, 320);
    k_attn<32><<<gNH,256,0,stream>>>(hf, as1, ad1, es, ed, N);
    k_fused<32><<<gNode,256,0,stream>>>(indptr, srcs, es, ed, hf, bc1, nfB, N);

    // GAT2: 32 -> H x 64
    k_gemm<32,0,1><<<dim3(gRow,640/64),256,0,stream>>>(nfB, Wc2, nullptr, hf, N, 640);
    k_attn<64><<<gNH,256,0,stream>>>(hf, as2, ad2, es, ed, N);
    k_fused<64><<<gNode,256,0,stream>>>(indptr, srcs, es, ed, hf, bc2, nfA, N);

    // GAT3: 64 -> H x 128
    k_gemm<64,0,1><<<dim3(gRow,1280/64),256,0,stream>>>(nfA, Wc3, nullptr, hf, N, 1280);
    k_attn<128><<<gNH,256,0,stream>>>(hf, as3, ad3, es, ed, N);
    k_fused<128><<<gNode,256,0,stream>>>(indptr, srcs, es, ed, hf, bc3, nfB, N);

    // fc1: [N,128]@[128,256] + bias + ELU (f32 out)
    k_gemm<128,1,0><<<dim3(gRow,256/64),256,0,stream>>>(nfB, W1, b1, nfA, N, 256);
    // head
    k_head<<<(N+7)/8,256,0,stream>>>(nfA, W2, b2, out, N);
}

// Round 12
// 298.160 us; speedup vs baseline: 1.4110x; 1.0232x over previous
//
#include <hip/hip_runtime.h>
#include <hip/hip_bf16.h>
#include <math.h>

#define NHEADS 10

typedef unsigned short ushort_t;
typedef unsigned int uint_t;

typedef __attribute__((ext_vector_type(4))) float f32x4;
typedef __attribute__((ext_vector_type(8))) short short8;

__device__ __forceinline__ float bu2f(ushort_t u){ return __uint_as_float(((uint_t)u)<<16); }
__device__ __forceinline__ ushort_t f2bu(float f){
    uint_t b = __float_as_uint(f);
    return (ushort_t)((b + 0x7FFFu + ((b>>16)&1u)) >> 16);   // RNE
}

// ---------------- CSR build ----------------
__global__ void k_count(const int* eidx, int E, int N, int* cnt){
    int e = blockIdx.x*blockDim.x + threadIdx.x;
    int ET = E + N;
    if(e >= ET) return;
    int d = (e < E) ? eidx[E + e] : (e - E);
    atomicAdd(&cnt[d], 1);
}

__global__ void k_scan(int* cnt, int N, int ET, int* indptr){
    __shared__ int lds[1024];
    int t = threadIdx.x;
    int chunk = (N + 1023)/1024;
    int base = t*chunk;
    int s = 0;
    for(int i=0;i<chunk;i++){ int idx=base+i; if(idx<N) s += cnt[idx]; }
    lds[t]=s;
    __syncthreads();
    for(int off=1; off<1024; off<<=1){
        int v = (t>=off)? lds[t-off] : 0;
        __syncthreads();
        lds[t]+=v;
        __syncthreads();
    }
    int run = lds[t]-s;
    for(int i=0;i<chunk;i++){
        int idx=base+i;
        if(idx<N){
            int c = cnt[idx];
            indptr[idx]=run;
            cnt[idx]=run;
            run += c;
        }
    }
    if(t==0) indptr[N]=ET;
}

__global__ void k_fill(const int* eidx, int E, int N, int* cursor, int* srcs){
    int e = blockIdx.x*blockDim.x + threadIdx.x;
    int ET = E + N;
    if(e >= ET) return;
    int s, d;
    if(e < E){ s = eidx[e]; d = eidx[E+e]; } else { s = e-E; d = e-E; }
    int pos = atomicAdd(&cursor[d], 1);
    srcs[pos] = s;
}

// wave-parallel bitonic sort of each node's src segment (1 wave / node)
__global__ void k_sortw(const int* indptr, int* srcs, int N){
    int wid  = (blockIdx.x*blockDim.x + threadIdx.x) >> 6;
    int lane = threadIdx.x & 63;
    if(wid >= N) return;
    int p0 = indptr[wid], p1 = indptr[wid+1];
    int deg = p1 - p0;
    if(deg <= 1) return;
    if(deg <= 64){
        int v = (lane < deg) ? srcs[p0+lane] : 0x7FFFFFFF;
        #pragma unroll
        for(int k=2; k<=64; k<<=1){
            #pragma unroll
            for(int j=k>>1; j>0; j>>=1){
                int partner = __shfl_xor(v, j, 64);
                bool dir   = ((lane & k) == 0);
                bool small = ((lane & j) == 0);
                int mn = min(v, partner), mx = max(v, partner);
                v = (dir == small) ? mn : mx;
            }
        }
        if(lane < deg) srcs[p0+lane] = v;
    } else if(lane == 0){               // safety fallback, statistically never
        for(int i=p0+1;i<p1;i++){
            int v2 = srcs[i]; int j=i-1;
            while(j>=p0 && srcs[j]>v2){ srcs[j+1]=srcs[j]; j--; }
            srcs[j+1]=v2;
        }
    }
}

// ---------------- weight transpose: WT[c][kp] = bf16(W[k][c]), zero-pad k>=K ----------------
__global__ void k_trans(const float* __restrict__ W, ushort_t* __restrict__ WT,
                        int K, int KP, int HC){
    int idx = blockIdx.x*blockDim.x + threadIdx.x;
    if(idx >= HC*KP) return;
    int c = idx / KP, k = idx % KP;
    WT[idx] = (k < K) ? f2bu(W[(size_t)k*HC + c]) : (ushort_t)0;
}

// ---------------- fc0: [N,24]@[24,16]+b, ELU ----------------
__global__ void k_fc0(const float* x, const float* W0, const float* b0, float* out, int N){
    int idx = blockIdx.x*blockDim.x+threadIdx.x;
    if(idx >= N*16) return;
    int n = idx>>4, c = idx&15;
    float acc = b0[c];
    #pragma unroll
    for(int k=0;k<24;k++) acc += x[n*24+k] * W0[k*16+c];
    out[idx] = acc>0.f ? acc : expm1f(acc);
}

// ---------------- LDS-free MFMA GEMM: C[N,HC] = A[N,K] @ B[K,HC] ----------------
// B pre-transposed+padded to BT[col][KP] bf16 (k_trans). 4 waves/block, wave = 16 rows x 64 cols.
// A frag: row=lane&15, k=(lane>>4)*8+j, f32->bf16 in-register. B frag: one b128 from BT (L2-hit).
// C/D: col=lane&15, row=(lane>>4)*4+reg  [verified R11: absmax identical to f32 path].
template<int K, int KP, int EPI, int OUTBF16>
__global__ void __launch_bounds__(256, 4)
k_gemm(const float* __restrict__ A, const ushort_t* __restrict__ BT,
       const float* __restrict__ bias, void* __restrict__ Cmat,
       int N, int HC){
    int t = threadIdx.x;
    int w = t >> 6, lane = t & 63;
    int lr = lane & 15, lk = lane >> 4;
    int row0 = blockIdx.x*64, col0 = blockIdx.y*64;
    int row = row0 + w*16 + lr;

    f32x4 acc[4];
    #pragma unroll
    for(int f=0; f<4; f++) acc[f] = (f32x4){0.f,0.f,0.f,0.f};

    #pragma unroll
    for(int kb = 0; kb < K; kb += 32){
        int k0 = kb + lk*8;
        short8 af = {0,0,0,0,0,0,0,0};
        if(row < N && k0 < K){
            const float* ap = &A[(size_t)row*K + k0];
            float4 a0 = *(const float4*)ap;
            float4 a1 = *(const float4*)(ap + 4);
            af[0]=(short)f2bu(a0.x); af[1]=(short)f2bu(a0.y);
            af[2]=(short)f2bu(a0.z); af[3]=(short)f2bu(a0.w);
            af[4]=(short)f2bu(a1.x); af[5]=(short)f2bu(a1.y);
            af[6]=(short)f2bu(a1.z); af[7]=(short)f2bu(a1.w);
        }
        #pragma unroll
        for(int f=0; f<4; f++){
            int col = col0 + f*16 + lr;
            short8 bf = *(const short8*)&BT[(size_t)col*KP + k0];
            acc[f] = __builtin_amdgcn_mfma_f32_16x16x32_bf16(af, bf, acc[f], 0, 0, 0);
        }
    }

    #pragma unroll
    for(int f=0; f<4; f++){
        #pragma unroll
        for(int j=0; j<4; j++){
            int r = row0 + w*16 + lk*4 + j;
            if(r >= N) continue;
            int col = col0 + f*16 + lr;
            float v = acc[f][j];
            if(EPI){
                v += bias[col];
                v = v>0.f ? v : expm1f(v);
            }
            if(OUTBF16) ((ushort_t*)Cmat)[(size_t)r*HC + col] = f2bu(v);
            else        ((float*)Cmat)[(size_t)r*HC + col] = v;
        }
    }
}

// ---------------- attention logits: 4 threads per (n,h), quarter-row each ----------------
template<int C>
__global__ void k_attn(const ushort_t* hf, const float* a_s, const float* a_d,
                       float* es, float* ed, int N){
    int tid = blockIdx.x*blockDim.x + threadIdx.x;
    if(tid >= N*NHEADS*4) return;
    int q   = tid & 3;
    int idx = tid >> 2;
    int n = idx/NHEADS, h = idx%NHEADS;
    constexpr int CQ = C/4;
    const ushort_t* hp = hf + (size_t)n*NHEADS*C + h*C + q*CQ;
    const float* asp = a_s + h*C + q*CQ;
    const float* adp = a_d + h*C + q*CQ;
    float s=0.f, d=0.f;
    #pragma unroll
    for(int cb=0; cb<CQ/8; cb++){
        uint4 qv = *(const uint4*)(hp + cb*8);
        uint_t uu[4] = {qv.x, qv.y, qv.z, qv.w};
        #pragma unroll
        for(int j=0;j<4;j++){
            float f0 = __uint_as_float(uu[j]<<16);
            float f1 = __uint_as_float(uu[j] & 0xFFFF0000u);
            int c = cb*8 + j*2;
            s += f0*asp[c] + f1*asp[c+1];
            d += f0*adp[c] + f1*adp[c+1];
        }
    }
    s += __shfl_xor(s, 1, 64); s += __shfl_xor(s, 2, 64);
    d += __shfl_xor(d, 1, 64); d += __shfl_xor(d, 2, 64);
    if(q == 0){ es[idx]=s; ed[idx]=d; }
}

// ---------------- fused softmax + aggregation (no-max-subtraction variant) ----------------
template<int C>
__global__ void __launch_bounds__(256, 4)
k_fused(const int* __restrict__ indptr, const int* __restrict__ srcs,
        const float* __restrict__ es, const float* __restrict__ ed,
        const ushort_t* __restrict__ hf, const float* __restrict__ bc,
        float* __restrict__ out, int N)
{
    __shared__ float wlds[4][64*NHEADS];
    __shared__ float stat[4][NHEADS];      // 1/den per head
    __shared__ int   degs[4];
    int wslot = threadIdx.x >> 6;
    int lane  = threadIdx.x & 63;
    int n = (blockIdx.x << 2) + wslot;
    bool valid = (n < N);
    int p0 = 0, deg = 0;
    if(valid){ p0 = indptr[n]; deg = indptr[n+1] - p0; }
    if(lane == 0) degs[wslot] = deg;
    __syncthreads();
    int maxdeg = max(max(degs[0],degs[1]), max(degs[2],degs[3]));
    int nch = (maxdeg + 63) >> 6;
    float* wl = wlds[wslot];

    int e6 = lane/10, h6 = lane%10;
    float edv = (valid && lane < 60) ? ed[n*NHEADS + h6] : 0.f;

    float den = 0.f;
    for(int c = 0; c < nch; c++){
        int base = c << 6;
        int lim = deg - base; if(lim > 64) lim = 64;
        if(valid && lane < 60){
            for(int i = e6; i < lim; i += 6){
                float v = es[(size_t)srcs[p0+base+i]*NHEADS + h6] + edv;
                v = (v >= 0.f) ? v : 0.2f*v;
                wl[i*NHEADS + h6] = expf(fminf(v, 60.f));
            }
        }
        __syncthreads();
        if(valid && lane < NHEADS){
            for(int i = 0; i < lim; i++) den += wl[i*NHEADS + lane];
        }
        if(nch > 1) __syncthreads();
    }
    if(valid && lane < NHEADS) stat[wslot][lane] = 1.f/(den + 1e-30f);
    __syncthreads();

    constexpr int TPN = C/8;
    constexpr int EG  = 64/TPN;
    int local = lane % TPN, eg = lane / TPN;
    int c8 = local*8;
    float dinv_r[NHEADS];
    #pragma unroll
    for(int h=0; h<NHEADS; h++) dinv_r[h] = stat[wslot][h];
    float acc[8];
    #pragma unroll
    for(int i=0;i<8;i++) acc[i]=0.f;

    for(int c = 0; c < nch; c++){
        int base = c << 6;
        int lim = deg - base; if(lim > 64) lim = 64;
        if(nch > 1){
            if(valid && lane < 60){
                for(int i = e6; i < lim; i += 6){
                    float v = es[(size_t)srcs[p0+base+i]*NHEADS + h6] + edv;
                    v = (v >= 0.f) ? v : 0.2f*v;
                    wl[i*NHEADS + h6] = expf(fminf(v, 60.f));
                }
            }
            __syncthreads();
        }
        if(valid){
            for(int i = eg; i < lim; i += EG){
                int s = srcs[p0+base+i];
                const ushort_t* hp = hf + (size_t)s*NHEADS*C + c8;
                const float* wp = &wl[i*NHEADS];
                #pragma unroll
                for(int h=0;h<NHEADS;h++){
                    uint4 q = *(const uint4*)(hp + h*C);
                    float wd = wp[h]*dinv_r[h];
                    acc[0] += wd * __uint_as_float(q.x<<16);
                    acc[1] += wd * __uint_as_float(q.x & 0xFFFF0000u);
                    acc[2] += wd * __uint_as_float(q.y<<16);
                    acc[3] += wd * __uint_as_float(q.y & 0xFFFF0000u);
                    acc[4] += wd * __uint_as_float(q.z<<16);
                    acc[5] += wd * __uint_as_float(q.z & 0xFFFF0000u);
                    acc[6] += wd * __uint_as_float(q.w<<16);
                    acc[7] += wd * __uint_as_float(q.w & 0xFFFF0000u);
                }
            }
        }
        if(nch > 1) __syncthreads();
    }

    #pragma unroll
    for(int s = TPN; s < 64; s <<= 1){
        #pragma unroll
        for(int i=0;i<8;i++) acc[i] += __shfl_xor(acc[i], s, 64);
    }
    if(valid && eg == 0){
        float4 v0, v1;
        #pragma unroll
        for(int i=0;i<8;i++){
            float v = acc[i]*(1.f/NHEADS) + bc[c8+i];
            v = v>0.f ? v : expm1f(v);
            if(i<4) ((float*)&v0)[i] = v; else ((float*)&v1)[i-4] = v;
        }
        *(float4*)&out[(size_t)n*C + c8]     = v0;
        *(float4*)&out[(size_t)n*C + c8 + 4] = v1;
    }
}

// ---------------- head: logits 256->24 + log_softmax ----------------
__global__ void k_head(const float* hin, const float* W2, const float* b2v, float* out, int N){
    int grp  = threadIdx.x/32;
    int lane = threadIdx.x%32;
    int n = blockIdx.x*8 + grp;
    if(n>=N) return;
    float acc = -1e30f;
    if(lane < 24){
        acc = b2v[lane];
        for(int k=0;k<256;k++) acc += hin[n*256+k]*W2[k*24+lane];
    }
    float mx = acc;
    for(int off=16; off; off>>=1) mx = fmaxf(mx, __shfl_xor(mx, off, 32));
    float ex = (lane<24)? expf(acc-mx) : 0.f;
    float sm = ex;
    for(int off=16; off; off>>=1) sm += __shfl_xor(sm, off, 32);
    if(lane<24) out[n*24+lane] = acc - mx - logf(sm);
}

extern "C" void kernel_launch(void* const* d_in, const int* in_sizes, int n_in,
                              void* d_out, int out_size, void* d_ws, size_t ws_size,
                              hipStream_t stream) {
    const float* x   = (const float*)d_in[0];
    const int*  eidx = (const int*)d_in[1];
    const float* W0 = (const float*)d_in[3];  const float* b0 = (const float*)d_in[4];
    const float* Wc1= (const float*)d_in[5];  const float* as1= (const float*)d_in[6];
    const float* ad1= (const float*)d_in[7];  const float* bc1= (const float*)d_in[8];
    const float* Wc2= (const float*)d_in[9];  const float* as2= (const float*)d_in[10];
    const float* ad2= (const float*)d_in[11]; const float* bc2= (const float*)d_in[12];
    const float* Wc3= (const float*)d_in[13]; const float* as3= (const float*)d_in[14];
    const float* ad3= (const float*)d_in[15]; const float* bc3= (const float*)d_in[16];
    const float* W1 = (const float*)d_in[17]; const float* b1 = (const float*)d_in[18];
    const float* W2 = (const float*)d_in[19]; const float* b2 = (const float*)d_in[20];
    float* out = (float*)d_out;

    const int N  = in_sizes[0]/24;
    const int E  = in_sizes[1]/2;
    const int ET = E + N;

    char* w = (char*)d_ws;
    size_t off = 0;
    auto alloc = [&](size_t bytes)->void* {
        void* p = w + off;
        off = (off + bytes + 255) & ~(size_t)255;
        return p;
    };
    int*   cnt    = (int*)  alloc((size_t)N*4);
    int*   indptr = (int*)  alloc((size_t)(N+1)*4);
    int*   srcs   = (int*)  alloc((size_t)ET*4);
    float* es     = (float*)alloc((size_t)N*NHEADS*4);
    float* ed     = (float*)alloc((size_t)N*NHEADS*4);
    float* nfA    = (float*)alloc((size_t)N*256*4);
    float* nfB    = (float*)alloc((size_t)N*256*4);
    ushort_t* hf  = (ushort_t*)alloc((size_t)N*1280*2);
    ushort_t* WT1 = (ushort_t*)alloc((size_t)320*32*2);
    ushort_t* WT2 = (ushort_t*)alloc((size_t)640*32*2);
    ushort_t* WT3 = (ushort_t*)alloc((size_t)1280*64*2);
    ushort_t* WT4 = (ushort_t*)alloc((size_t)256*128*2);

    // weight transposes (bf16, k-padded)
    k_trans<<<(320*32+255)/256,256,0,stream>>>(Wc1, WT1, 16, 32, 320);
    k_trans<<<(640*32+255)/256,256,0,stream>>>(Wc2, WT2, 32, 32, 640);
    k_trans<<<(1280*64+255)/256,256,0,stream>>>(Wc3, WT3, 64, 64, 1280);
    k_trans<<<(256*128+255)/256,256,0,stream>>>(W1, WT4, 128, 128, 256);

    // CSR by dst
    hipMemsetAsync(cnt, 0, (size_t)N*4, stream);
    int gE = (ET+255)/256;
    k_count<<<gE,256,0,stream>>>(eidx, E, N, cnt);
    k_scan <<<1,1024,0,stream>>>(cnt, N, ET, indptr);
    k_fill <<<gE,256,0,stream>>>(eidx, E, N, cnt, srcs);
    k_sortw<<<((size_t)N*64+255)/256,256,0,stream>>>(indptr, srcs, N);

    int gA   = (N*NHEADS*4+255)/256;
    int gRow = (N+63)/64;
    int gNode = (N+3)/4;

    // fc0
    k_fc0<<<(N*16+255)/256,256,0,stream>>>(x, W0, b0, nfA, N);

    // GAT1: 16 -> H x 32
    k_gemm<16,32,0,1><<<dim3(gRow,320/64),256,0,stream>>>(nfA, WT1, nullptr, hf, N, 320);
    k_attn<32><<<gA,256,0,stream>>>(hf, as1, ad1, es, ed, N);
    k_fused<32><<<gNode,256,0,stream>>>(indptr, srcs, es, ed, hf, bc1, nfB, N);

    // GAT2: 32 -> H x 64
    k_gemm<32,32,0,1><<<dim3(gRow,640/64),256,0,stream>>>(nfB, WT2, nullptr, hf, N, 640);
    k_attn<64><<<gA,256,0,stream>>>(hf, as2, ad2, es, ed, N);
    k_fused<64><<<gNode,256,0,stream>>>(indptr, srcs, es, ed, hf, bc2, nfA, N);

    // GAT3: 64 -> H x 128
    k_gemm<64,64,0,1><<<dim3(gRow,1280/64),256,0,stream>>>(nfA, WT3, nullptr, hf, N, 1280);
    k_attn<128><<<gA,256,0,stream>>>(hf, as3, ad3, es, ed, N);
    k_fused<128><<<gNode,256,0,stream>>>(indptr, srcs, es, ed, hf, bc3, nfB, N);

    // fc1: [N,128]@[128,256] + bias + ELU (f32 out)
    k_gemm<128,128,1,0><<<dim3(gRow,256/64),256,0,stream>>>(nfB, WT4, b1, nfA, N, 256);
    // head
    k_head<<<(N+7)/8,256,0,stream>>>(nfA, W2, b2, out, N);
}

// Round 13
// 293.574 us; speedup vs baseline: 1.4331x; 1.0156x over previous
//
#include <hip/hip_runtime.h>
#include <hip/hip_bf16.h>
#include <math.h>

#define NHEADS 10

typedef unsigned short ushort_t;
typedef unsigned int uint_t;

typedef __attribute__((ext_vector_type(4))) float f32x4;
typedef __attribute__((ext_vector_type(8))) short short8;

__device__ __forceinline__ float bu2f(ushort_t u){ return __uint_as_float(((uint_t)u)<<16); }
__device__ __forceinline__ ushort_t f2bu(float f){
    uint_t b = __float_as_uint(f);
    return (ushort_t)((b + 0x7FFFu + ((b>>16)&1u)) >> 16);   // RNE
}

// ---------------- CSR build ----------------
__global__ void k_count(const int* eidx, int E, int N, int* cnt){
    int e = blockIdx.x*blockDim.x + threadIdx.x;
    int ET = E + N;
    if(e >= ET) return;
    int d = (e < E) ? eidx[E + e] : (e - E);
    atomicAdd(&cnt[d], 1);
}

__global__ void k_scan(int* cnt, int N, int ET, int* indptr){
    __shared__ int lds[1024];
    int t = threadIdx.x;
    int chunk = (N + 1023)/1024;
    int base = t*chunk;
    int s = 0;
    for(int i=0;i<chunk;i++){ int idx=base+i; if(idx<N) s += cnt[idx]; }
    lds[t]=s;
    __syncthreads();
    for(int off=1; off<1024; off<<=1){
        int v = (t>=off)? lds[t-off] : 0;
        __syncthreads();
        lds[t]+=v;
        __syncthreads();
    }
    int run = lds[t]-s;
    for(int i=0;i<chunk;i++){
        int idx=base+i;
        if(idx<N){
            int c = cnt[idx];
            indptr[idx]=run;
            cnt[idx]=run;
            run += c;
        }
    }
    if(t==0) indptr[N]=ET;
}

__global__ void k_fill(const int* eidx, int E, int N, int* cursor, int* srcs){
    int e = blockIdx.x*blockDim.x + threadIdx.x;
    int ET = E + N;
    if(e >= ET) return;
    int s, d;
    if(e < E){ s = eidx[e]; d = eidx[E+e]; } else { s = e-E; d = e-E; }
    int pos = atomicAdd(&cursor[d], 1);
    srcs[pos] = s;
}

// wave-parallel bitonic sort of each node's src segment (1 wave / node)
__global__ void k_sortw(const int* indptr, int* srcs, int N){
    int wid  = (blockIdx.x*blockDim.x + threadIdx.x) >> 6;
    int lane = threadIdx.x & 63;
    if(wid >= N) return;
    int p0 = indptr[wid], p1 = indptr[wid+1];
    int deg = p1 - p0;
    if(deg <= 1) return;
    if(deg <= 64){
        int v = (lane < deg) ? srcs[p0+lane] : 0x7FFFFFFF;
        #pragma unroll
        for(int k=2; k<=64; k<<=1){
            #pragma unroll
            for(int j=k>>1; j>0; j>>=1){
                int partner = __shfl_xor(v, j, 64);
                bool dir   = ((lane & k) == 0);
                bool small = ((lane & j) == 0);
                int mn = min(v, partner), mx = max(v, partner);
                v = (dir == small) ? mn : mx;
            }
        }
        if(lane < deg) srcs[p0+lane] = v;
    } else if(lane == 0){               // safety fallback, statistically never
        for(int i=p0+1;i<p1;i++){
            int v2 = srcs[i]; int j=i-1;
            while(j>=p0 && srcs[j]>v2){ srcs[j+1]=srcs[j]; j--; }
            srcs[j+1]=v2;
        }
    }
}

// ---------------- all weight transposes in one dispatch ----------------
__global__ void k_trans_all(const float* __restrict__ W1c,const float* __restrict__ W2c,
                            const float* __restrict__ W3c,const float* __restrict__ W4c,
                            ushort_t* T1,ushort_t* T2,ushort_t* T3,ushort_t* T4){
    int idx = blockIdx.x*blockDim.x + threadIdx.x;
    if(idx < 10240){ int c=idx/32, k=idx%32; T1[idx] = (k<16)? f2bu(W1c[(size_t)k*320+c]) : (ushort_t)0; return; }
    idx -= 10240;
    if(idx < 20480){ int c=idx/32, k=idx%32; T2[idx] = f2bu(W2c[(size_t)k*640+c]); return; }
    idx -= 20480;
    if(idx < 81920){ int c=idx/64, k=idx%64; T3[idx] = f2bu(W3c[(size_t)k*1280+c]); return; }
    idx -= 81920;
    if(idx < 32768){ int c=idx/128, k=idx%128; T4[idx] = f2bu(W4c[(size_t)k*256+c]); return; }
}

// ---------------- fc0: [N,24]@[24,16]+b, ELU ----------------
__global__ void k_fc0(const float* x, const float* W0, const float* b0, float* out, int N){
    int idx = blockIdx.x*blockDim.x+threadIdx.x;
    if(idx >= N*16) return;
    int n = idx>>4, c = idx&15;
    float acc = b0[c];
    #pragma unroll
    for(int k=0;k<24;k++) acc += x[n*24+k] * W0[k*16+c];
    out[idx] = acc>0.f ? acc : expm1f(acc);
}

// ---------------- LDS-free MFMA GEMM (verified R11/R12) ----------------
template<int K, int KP, int EPI, int OUTBF16>
__global__ void __launch_bounds__(256, 4)
k_gemm(const float* __restrict__ A, const ushort_t* __restrict__ BT,
       const float* __restrict__ bias, void* __restrict__ Cmat,
       int N, int HC){
    int t = threadIdx.x;
    int w = t >> 6, lane = t & 63;
    int lr = lane & 15, lk = lane >> 4;
    int row0 = blockIdx.x*64, col0 = blockIdx.y*64;
    int row = row0 + w*16 + lr;

    f32x4 acc[4];
    #pragma unroll
    for(int f=0; f<4; f++) acc[f] = (f32x4){0.f,0.f,0.f,0.f};

    #pragma unroll
    for(int kb = 0; kb < K; kb += 32){
        int k0 = kb + lk*8;
        short8 af = {0,0,0,0,0,0,0,0};
        if(row < N && k0 < K){
            const float* ap = &A[(size_t)row*K + k0];
            float4 a0 = *(const float4*)ap;
            float4 a1 = *(const float4*)(ap + 4);
            af[0]=(short)f2bu(a0.x); af[1]=(short)f2bu(a0.y);
            af[2]=(short)f2bu(a0.z); af[3]=(short)f2bu(a0.w);
            af[4]=(short)f2bu(a1.x); af[5]=(short)f2bu(a1.y);
            af[6]=(short)f2bu(a1.z); af[7]=(short)f2bu(a1.w);
        }
        #pragma unroll
        for(int f=0; f<4; f++){
            int col = col0 + f*16 + lr;
            short8 bf = *(const short8*)&BT[(size_t)col*KP + k0];
            acc[f] = __builtin_amdgcn_mfma_f32_16x16x32_bf16(af, bf, acc[f], 0, 0, 0);
        }
    }

    #pragma unroll
    for(int f=0; f<4; f++){
        #pragma unroll
        for(int j=0; j<4; j++){
            int r = row0 + w*16 + lk*4 + j;
            if(r >= N) continue;
            int col = col0 + f*16 + lr;
            float v = acc[f][j];
            if(EPI){
                v += bias[col];
                v = v>0.f ? v : expm1f(v);
            }
            if(OUTBF16) ((ushort_t*)Cmat)[(size_t)r*HC + col] = f2bu(v);
            else        ((float*)Cmat)[(size_t)r*HC + col] = v;
        }
    }
}

// ---------------- attention logits: 4 threads per (n,h) ----------------
template<int C>
__global__ void k_attn(const ushort_t* hf, const float* a_s, const float* a_d,
                       float* es, float* ed, int N){
    int tid = blockIdx.x*blockDim.x + threadIdx.x;
    if(tid >= N*NHEADS*4) return;
    int q   = tid & 3;
    int idx = tid >> 2;
    int n = idx/NHEADS, h = idx%NHEADS;
    constexpr int CQ = C/4;
    const ushort_t* hp = hf + (size_t)n*NHEADS*C + h*C + q*CQ;
    const float* asp = a_s + h*C + q*CQ;
    const float* adp = a_d + h*C + q*CQ;
    float s=0.f, d=0.f;
    #pragma unroll
    for(int cb=0; cb<CQ/8; cb++){
        uint4 qv = *(const uint4*)(hp + cb*8);
        uint_t uu[4] = {qv.x, qv.y, qv.z, qv.w};
        #pragma unroll
        for(int j=0;j<4;j++){
            float f0 = __uint_as_float(uu[j]<<16);
            float f1 = __uint_as_float(uu[j] & 0xFFFF0000u);
            int c = cb*8 + j*2;
            s += f0*asp[c] + f1*asp[c+1];
            d += f0*adp[c] + f1*adp[c+1];
        }
    }
    s += __shfl_xor(s, 1, 64); s += __shfl_xor(s, 2, 64);
    d += __shfl_xor(d, 1, 64); d += __shfl_xor(d, 2, 64);
    if(q == 0){ es[idx]=s; ed[idx]=d; }
}

// ---------------- fused softmax + aggregation, src-window phased gather ----------------
// Weights pass identical to R12. Gather pass walks each lane-group's (sorted) edge
// subsequence split into P src-windows sized ~L2, so all resident blocks sweep the same
// window of hf quasi-simultaneously (same FP order -> bit-identical output).
template<int C, int P>
__global__ void __launch_bounds__(256, 4)
k_fused(const int* __restrict__ indptr, const int* __restrict__ srcs,
        const float* __restrict__ es, const float* __restrict__ ed,
        const ushort_t* __restrict__ hf, const float* __restrict__ bc,
        float* __restrict__ out, int N)
{
    __shared__ float wlds[4][64*NHEADS];
    __shared__ float stat[4][NHEADS];
    __shared__ int   degs[4];
    int wslot = threadIdx.x >> 6;
    int lane  = threadIdx.x & 63;
    int n = (blockIdx.x << 2) + wslot;
    bool valid = (n < N);
    int p0 = 0, deg = 0;
    if(valid){ p0 = indptr[n]; deg = indptr[n+1] - p0; }
    if(lane == 0) degs[wslot] = deg;
    __syncthreads();
    int maxdeg = max(max(degs[0],degs[1]), max(degs[2],degs[3]));
    int nch = (maxdeg + 63) >> 6;
    float* wl = wlds[wslot];

    int e6 = lane/10, h6 = lane%10;
    float edv = (valid && lane < 60) ? ed[n*NHEADS + h6] : 0.f;

    // ---- pass A: w = exp(leaky(e)) into LDS; serial per-head den ----
    float den = 0.f;
    for(int c = 0; c < nch; c++){
        int base = c << 6;
        int lim = deg - base; if(lim > 64) lim = 64;
        if(valid && lane < 60){
            for(int i = e6; i < lim; i += 6){
                float v = es[(size_t)srcs[p0+base+i]*NHEADS + h6] + edv;
                v = (v >= 0.f) ? v : 0.2f*v;
                wl[i*NHEADS + h6] = expf(fminf(v, 60.f));
            }
        }
        __syncthreads();
        if(valid && lane < NHEADS){
            for(int i = 0; i < lim; i++) den += wl[i*NHEADS + lane];
        }
        if(nch > 1) __syncthreads();
    }
    if(valid && lane < NHEADS) stat[wslot][lane] = 1.f/(den + 1e-30f);
    __syncthreads();

    constexpr int TPN = C/8;
    constexpr int EG  = 64/TPN;
    int local = lane % TPN, eg = lane / TPN;
    int c8 = local*8;
    float dinv_r[NHEADS];
    #pragma unroll
    for(int h=0; h<NHEADS; h++) dinv_r[h] = stat[wslot][h];
    float acc[8];
    #pragma unroll
    for(int i=0;i<8;i++) acc[i]=0.f;

    if(nch == 1){
        // ---- phased gather (common path) ----
        int lim = deg;
        int win = (N + P - 1)/P;
        int i = eg;
        for(int ph = 0; ph < P; ph++){
            int bound = win*(ph+1);
            while(i < lim && srcs[p0+i] < bound){
                int s = srcs[p0+i];
                const ushort_t* hp = hf + (size_t)s*NHEADS*C + c8;
                const float* wp = &wl[i*NHEADS];
                #pragma unroll
                for(int h=0;h<NHEADS;h++){
                    uint4 q = *(const uint4*)(hp + h*C);
                    float wd = wp[h]*dinv_r[h];
                    acc[0] += wd * __uint_as_float(q.x<<16);
                    acc[1] += wd * __uint_as_float(q.x & 0xFFFF0000u);
                    acc[2] += wd * __uint_as_float(q.y<<16);
                    acc[3] += wd * __uint_as_float(q.y & 0xFFFF0000u);
                    acc[4] += wd * __uint_as_float(q.z<<16);
                    acc[5] += wd * __uint_as_float(q.z & 0xFFFF0000u);
                    acc[6] += wd * __uint_as_float(q.w<<16);
                    acc[7] += wd * __uint_as_float(q.w & 0xFFFF0000u);
                }
                i += EG;
            }
            __syncthreads();   // keep the block's waves in the same src window
        }
    } else {
        // ---- fallback chunked path (deg > 64; statistically never) ----
        for(int c = 0; c < nch; c++){
            int base = c << 6;
            int lim = deg - base; if(lim > 64) lim = 64;
            if(c > 0){
                if(valid && lane < 60){
                    for(int i = e6; i < lim; i += 6){
                        float v = es[(size_t)srcs[p0+base+i]*NHEADS + h6] + edv;
                        v = (v >= 0.f) ? v : 0.2f*v;
                        wl[i*NHEADS + h6] = expf(fminf(v, 60.f)) * dinv_r[h6];
                    }
                }
                __syncthreads();
            }
            if(valid){
                for(int i = eg; i < lim; i += EG){
                    int s = srcs[p0+base+i];
                    const ushort_t* hp = hf + (size_t)s*NHEADS*C + c8;
                    const float* wp = &wl[i*NHEADS];
                    float fac = (c == 0) ? 1.f : (1.f/1.f);
                    #pragma unroll
                    for(int h=0;h<NHEADS;h++){
                        uint4 q = *(const uint4*)(hp + h*C);
                        float wd = (c == 0) ? wp[h]*dinv_r[h] : wp[h];
                        acc[0] += wd * __uint_as_float(q.x<<16);
                        acc[1] += wd * __uint_as_float(q.x & 0xFFFF0000u);
                        acc[2] += wd * __uint_as_float(q.y<<16);
                        acc[3] += wd * __uint_as_float(q.y & 0xFFFF0000u);
                        acc[4] += wd * __uint_as_float(q.z<<16);
                        acc[5] += wd * __uint_as_float(q.z & 0xFFFF0000u);
                        acc[6] += wd * __uint_as_float(q.w<<16);
                        acc[7] += wd * __uint_as_float(q.w & 0xFFFF0000u);
                    }
                    (void)fac;
                }
            }
            __syncthreads();
        }
    }

    #pragma unroll
    for(int s = TPN; s < 64; s <<= 1){
        #pragma unroll
        for(int i=0;i<8;i++) acc[i] += __shfl_xor(acc[i], s, 64);
    }
    if(valid && eg == 0){
        float4 v0, v1;
        #pragma unroll
        for(int i=0;i<8;i++){
            float v = acc[i]*(1.f/NHEADS) + bc[c8+i];
            v = v>0.f ? v : expm1f(v);
            if(i<4) ((float*)&v0)[i] = v; else ((float*)&v1)[i-4] = v;
        }
        *(float4*)&out[(size_t)n*C + c8]     = v0;
        *(float4*)&out[(size_t)n*C + c8 + 4] = v1;
    }
}

// ---------------- head: logits 256->24 + log_softmax ----------------
__global__ void k_head(const float* hin, const float* W2, const float* b2v, float* out, int N){
    int grp  = threadIdx.x/32;
    int lane = threadIdx.x%32;
    int n = blockIdx.x*8 + grp;
    if(n>=N) return;
    float acc = -1e30f;
    if(lane < 24){
        acc = b2v[lane];
        for(int k=0;k<256;k++) acc += hin[n*256+k]*W2[k*24+lane];
    }
    float mx = acc;
    for(int off=16; off; off>>=1) mx = fmaxf(mx, __shfl_xor(mx, off, 32));
    float ex = (lane<24)? expf(acc-mx) : 0.f;
    float sm = ex;
    for(int off=16; off; off>>=1) sm += __shfl_xor(sm, off, 32);
    if(lane<24) out[n*24+lane] = acc - mx - logf(sm);
}

extern "C" void kernel_launch(void* const* d_in, const int* in_sizes, int n_in,
                              void* d_out, int out_size, void* d_ws, size_t ws_size,
                              hipStream_t stream) {
    const float* x   = (const float*)d_in[0];
    const int*  eidx = (const int*)d_in[1];
    const float* W0 = (const float*)d_in[3];  const float* b0 = (const float*)d_in[4];
    const float* Wc1= (const float*)d_in[5];  const float* as1= (const float*)d_in[6];
    const float* ad1= (const float*)d_in[7];  const float* bc1= (const float*)d_in[8];
    const float* Wc2= (const float*)d_in[9];  const float* as2= (const float*)d_in[10];
    const float* ad2= (const float*)d_in[11]; const float* bc2= (const float*)d_in[12];
    const float* Wc3= (const float*)d_in[13]; const float* as3= (const float*)d_in[14];
    const float* ad3= (const float*)d_in[15]; const float* bc3= (const float*)d_in[16];
    const float* W1 = (const float*)d_in[17]; const float* b1 = (const float*)d_in[18];
    const float* W2 = (const float*)d_in[19]; const float* b2 = (const float*)d_in[20];
    float* out = (float*)d_out;

    const int N  = in_sizes[0]/24;
    const int E  = in_sizes[1]/2;
    const int ET = E + N;

    char* w = (char*)d_ws;
    size_t off = 0;
    auto alloc = [&](size_t bytes)->void* {
        void* p = w + off;
        off = (off + bytes + 255) & ~(size_t)255;
        return p;
    };
    int*   cnt    = (int*)  alloc((size_t)N*4);
    int*   indptr = (int*)  alloc((size_t)(N+1)*4);
    int*   srcs   = (int*)  alloc((size_t)ET*4);
    float* es     = (float*)alloc((size_t)N*NHEADS*4);
    float* ed     = (float*)alloc((size_t)N*NHEADS*4);
    float* nfA    = (float*)alloc((size_t)N*256*4);
    float* nfB    = (float*)alloc((size_t)N*256*4);
    ushort_t* hf  = (ushort_t*)alloc((size_t)N*1280*2);
    ushort_t* WT1 = (ushort_t*)alloc((size_t)320*32*2);
    ushort_t* WT2 = (ushort_t*)alloc((size_t)640*32*2);
    ushort_t* WT3 = (ushort_t*)alloc((size_t)1280*64*2);
    ushort_t* WT4 = (ushort_t*)alloc((size_t)256*128*2);

    // weight transposes (bf16, k-padded), single dispatch
    k_trans_all<<<(145408+255)/256,256,0,stream>>>(Wc1, Wc2, Wc3, W1, WT1, WT2, WT3, WT4);

    // CSR by dst
    hipMemsetAsync(cnt, 0, (size_t)N*4, stream);
    int gE = (ET+255)/256;
    k_count<<<gE,256,0,stream>>>(eidx, E, N, cnt);
    k_scan <<<1,1024,0,stream>>>(cnt, N, ET, indptr);
    k_fill <<<gE,256,0,stream>>>(eidx, E, N, cnt, srcs);
    k_sortw<<<((size_t)N*64+255)/256,256,0,stream>>>(indptr, srcs, N);

    int gA   = (N*NHEADS*4+255)/256;
    int gRow = (N+63)/64;
    int gNode = (N+3)/4;

    // fc0
    k_fc0<<<(N*16+255)/256,256,0,stream>>>(x, W0, b0, nfA, N);

    // GAT1: 16 -> H x 32   (hf = 6.4 MB, P=2)
    k_gemm<16,32,0,1><<<dim3(gRow,320/64),256,0,stream>>>(nfA, WT1, nullptr, hf, N, 320);
    k_attn<32><<<gA,256,0,stream>>>(hf, as1, ad1, es, ed, N);
    k_fused<32,2><<<gNode,256,0,stream>>>(indptr, srcs, es, ed, hf, bc1, nfB, N);

    // GAT2: 32 -> H x 64   (hf = 12.8 MB, P=4)
    k_gemm<32,32,0,1><<<dim3(gRow,640/64),256,0,stream>>>(nfB, WT2, nullptr, hf, N, 640);
    k_attn<64><<<gA,256,0,stream>>>(hf, as2, ad2, es, ed, N);
    k_fused<64,4><<<gNode,256,0,stream>>>(indptr, srcs, es, ed, hf, bc2, nfA, N);

    // GAT3: 64 -> H x 128  (hf = 25.6 MB, P=8)
    k_gemm<64,64,0,1><<<dim3(gRow,1280/64),256,0,stream>>>(nfA, WT3, nullptr, hf, N, 1280);
    k_attn<128><<<gA,256,0,stream>>>(hf, as3, ad3, es, ed, N);
    k_fused<128,8><<<gNode,256,0,stream>>>(indptr, srcs, es, ed, hf, bc3, nfB, N);

    // fc1: [N,128]@[128,256] + bias + ELU (f32 out)
    k_gemm<128,128,1,0><<<dim3(gRow,256/64),256,0,stream>>>(nfB, WT4, b1, nfA, N, 256);
    // head
    k_head<<<(N+7)/8,256,0,stream>>>(nfA, W2, b2, out, N);
}